// Round 2
// baseline (8377.366 us; speedup 1.0000x reference)
//
#include <hip/hip_runtime.h>
#include <hip/hip_bf16.h>
#include <math.h>

#define CDIV(a, b) (((a) + (b) - 1) / (b))

constexpr int Bn = 32;    // batch
constexpr int Sn = 720;   // seq len
constexpr int Cn = 2048;  // channels (tokens after transpose)
constexpr int Dn = 256;   // d_model
constexpr int Pn = 96;    // pred len

// ---------------- instance norm stats over time axis ----------------
__global__ void instnorm_stats(const float* __restrict__ x,
                               float* __restrict__ mean, float* __restrict__ stdev) {
  int c = blockIdx.x * 256 + threadIdx.x;
  int b = blockIdx.y;
  const float* p = x + (long long)b * Sn * Cn + c;
  float s = 0.f, q = 0.f;
  for (int t = 0; t < Sn; ++t) {
    float v = p[(long long)t * Cn];
    s += v; q += v * v;
  }
  float m = s / (float)Sn;
  float var = q / (float)Sn - m * m;
  var = fmaxf(var, 0.f);
  mean[b * Cn + c] = m;
  stdev[b * Cn + c] = sqrtf(var + 1e-5f);
}

__global__ void wsum_kernel(const float* __restrict__ w, float* __restrict__ ws) {
  int d = threadIdx.x;
  float s = 0.f;
  for (int t = 0; t < Sn; ++t) s += w[t * Dn + d];
  ws[d] = s;
}

// ---------------- generic tiled GEMM ----------------
// C[m,n] = epi( sum_k opA(A)[m,k] * opB(B)[k,n] )
// TRANSA=0: A row-major [M,K]. TRANSA=1: A stored [K,M] (lda=M-stride).
// TRANSB=0: B row-major [K,N]. TRANSB=1: B row-major [N,K].
// EPI: 0 = +bias(optional) ; 1 = *alpha ; 2 = instance-norm epilogue
template <int TRANSA, int TRANSB, int EPI>
__global__ __launch_bounds__(256) void gemm_kernel(
    const float* __restrict__ A, const float* __restrict__ Bm, float* __restrict__ Cc,
    const float* __restrict__ bias, int M, int N, int K, int lda, int ldb, int ldc,
    long long sA, long long sB, long long sC, float alpha,
    const float* __restrict__ aux0, const float* __restrict__ aux1,
    const float* __restrict__ aux2) {
  int g = blockIdx.z;
  A += (long long)g * sA;
  Bm += (long long)g * sB;
  Cc += (long long)g * sC;
  __shared__ float As[16][68];
  __shared__ float Bs[16][68];
  int t = threadIdx.x;
  int tx = t & 15, ty = t >> 4;
  int m0 = blockIdx.y * 64, n0 = blockIdx.x * 64;
  float acc[4][4] = {};
  for (int k0 = 0; k0 < K; k0 += 16) {
    if (TRANSA == 0) {
      int mm = t >> 4, kk = t & 15;
#pragma unroll
      for (int r = 0; r < 4; ++r) {
        int m = mm + r * 16;
        float v = 0.f;
        if (m0 + m < M) v = A[(long long)(m0 + m) * lda + k0 + kk];
        As[kk][m] = v;
      }
    } else {
      int kk = t >> 6, mm = t & 63;
#pragma unroll
      for (int r = 0; r < 4; ++r) {
        int k = kk + r * 4;
        float v = 0.f;
        if (m0 + mm < M) v = A[(long long)(k0 + k) * lda + m0 + mm];
        As[k][mm] = v;
      }
    }
    if (TRANSB == 0) {
      int kk = t >> 6, nn = t & 63;
#pragma unroll
      for (int r = 0; r < 4; ++r) {
        int k = kk + r * 4;
        float v = 0.f;
        if (n0 + nn < N) v = Bm[(long long)(k0 + k) * ldb + n0 + nn];
        Bs[k][nn] = v;
      }
    } else {
      int nn = t >> 4, kk = t & 15;
#pragma unroll
      for (int r = 0; r < 4; ++r) {
        int n = nn + r * 16;
        float v = 0.f;
        if (n0 + n < N) v = Bm[(long long)(n0 + n) * ldb + k0 + kk];
        Bs[kk][n] = v;
      }
    }
    __syncthreads();
#pragma unroll
    for (int k = 0; k < 16; ++k) {
      float a[4], bb[4];
#pragma unroll
      for (int i = 0; i < 4; ++i) a[i] = As[k][ty * 4 + i];
#pragma unroll
      for (int j = 0; j < 4; ++j) bb[j] = Bs[k][tx * 4 + j];
#pragma unroll
      for (int i = 0; i < 4; ++i)
#pragma unroll
        for (int j = 0; j < 4; ++j) acc[i][j] += a[i] * bb[j];
    }
    __syncthreads();
  }
#pragma unroll
  for (int i = 0; i < 4; ++i) {
    int m = m0 + ty * 4 + i;
    if (m >= M) continue;
#pragma unroll
    for (int j = 0; j < 4; ++j) {
      int n = n0 + tx * 4 + j;
      if (n >= N) continue;
      float v = acc[i][j];
      if (EPI == 0) {
        if (bias) v += bias[n];
      } else if (EPI == 1) {
        v *= alpha;
      } else if (EPI == 2) {
        float mu = aux0[(long long)g * M + m];
        float sd = aux1[(long long)g * M + m];
        v = (v - mu * aux2[n]) / sd + bias[n];
      }
      Cc[(long long)m * ldc + n] = v;
    }
  }
}

// ---------------- block reduction helper (blockDim = 256) ----------------
__device__ inline float blk_reduce(float v, volatile float* sh, int op) {
  int lane = threadIdx.x & 63, w = threadIdx.x >> 6;
#pragma unroll
  for (int off = 32; off > 0; off >>= 1) {
    float o = __shfl_down(v, off, 64);
    v = op ? fmaxf(v, o) : (v + o);
  }
  __syncthreads();
  if (lane == 0) sh[w] = v;
  __syncthreads();
  float r = op ? fmaxf(fmaxf(sh[0], sh[1]), fmaxf(sh[2], sh[3]))
               : (sh[0] + sh[1] + sh[2] + sh[3]);
  return r;
}

// ---------------- row softmax (in place) ----------------
__global__ void softmax_kernel(float* __restrict__ S, int L) {
  __shared__ float sh[4];
  long long row = blockIdx.x;
  float* p = S + row * (long long)L;
  int t = threadIdx.x;
  float mx = -INFINITY;
  for (int i = t; i < L; i += 256) mx = fmaxf(mx, p[i]);
  mx = blk_reduce(mx, sh, 1);
  float sum = 0.f;
  for (int i = t; i < L; i += 256) {
    float e = __expf(p[i] - mx);
    p[i] = e;
    sum += e;
  }
  sum = blk_reduce(sum, sh, 0);
  float inv = 1.f / sum;
  for (int i = t; i < L; i += 256) p[i] *= inv;
}

// ---------------- LayerNorm over D=256, optional residual ----------------
__global__ void ln_kernel(const float* __restrict__ X, const float* __restrict__ RES,
                          float* __restrict__ Y, const float* __restrict__ gamma,
                          const float* __restrict__ beta) {
  __shared__ float sh[4];
  long long row = blockIdx.x;
  int t = threadIdx.x;
  float v = X[row * Dn + t];
  if (RES) v += RES[row * Dn + t];
  float m = blk_reduce(v, sh, 0) * (1.f / (float)Dn);
  float d = v - m;
  float var = blk_reduce(d * d, sh, 0) * (1.f / (float)Dn);
  Y[row * Dn + t] = d * rsqrtf(var + 1e-5f) * gamma[t] + beta[t];
}

// ---------------- covariance column stats (f64 partials) ----------------
__global__ void colstat_partial(const float* __restrict__ X, double* __restrict__ part,
                                int nrows) {
  int blk = blockIdx.x, t = threadIdx.x;
  int chunk = CDIV(nrows, 64);
  int r0 = blk * chunk, r1 = min(nrows, r0 + chunk);
  double s = 0.0, q = 0.0;
  for (int r = r0; r < r1; ++r) {
    double v = (double)X[(long long)r * Dn + t];
    s += v; q += v * v;
  }
  part[blk * 512 + t] = s;
  part[blk * 512 + 256 + t] = q;
}

__global__ void colstat_final(const double* __restrict__ part, float* __restrict__ cmean,
                              float* __restrict__ cistd, int nrows) {
  int t = threadIdx.x;
  double s = 0.0, q = 0.0;
  for (int b = 0; b < 64; ++b) {
    s += part[b * 512 + t];
    q += part[b * 512 + 256 + t];
  }
  double m = s / (double)nrows;
  double var = (q - (double)nrows * m * m) / (double)(nrows - 1);
  var = fmax(var, 0.0);
  cmean[t] = (float)m;
  cistd[t] = (float)(1.0 / (sqrt(var) + 1e-5));
}

__global__ void xcnorm_kernel(const float* __restrict__ X, float* __restrict__ XC,
                              const float* __restrict__ cmean,
                              const float* __restrict__ cistd, long long n) {
  for (long long i = blockIdx.x * 256LL + threadIdx.x; i < n;
       i += (long long)gridDim.x * 256) {
    int d = (int)(i & 255);
    XC[i] = (X[i] - cmean[d]) * cistd[d];
  }
}

// ---------------- cov Gram matrix with f64 accumulation ----------------
// C[m,n] = (1/(nr-1)) * sum_k XC[k][m]*XC[k][n] + eps*(m==n)
__global__ __launch_bounds__(256) void cov_gemm_f64(const float* __restrict__ XC,
                                                    double* __restrict__ C, int nr,
                                                    double inv) {
  __shared__ float Am[32][33];
  __shared__ float Bq[32][33];
  int t = threadIdx.x;
  int tx = t & 31, ty = t >> 5;  // ty: 0..7
  int m0 = blockIdx.y * 32, n0 = blockIdx.x * 32;
  double acc[4] = {0.0, 0.0, 0.0, 0.0};
  for (int k0 = 0; k0 < nr; k0 += 32) {
#pragma unroll
    for (int e = 0; e < 4; ++e) {
      int idx = t + e * 256;
      int kk = idx >> 5, mm = idx & 31;
      Am[kk][mm] = XC[(long long)(k0 + kk) * Dn + m0 + mm];
      Bq[kk][mm] = XC[(long long)(k0 + kk) * Dn + n0 + mm];
    }
    __syncthreads();
#pragma unroll 8
    for (int kk = 0; kk < 32; ++kk) {
      float bv = Bq[kk][tx];
#pragma unroll
      for (int r = 0; r < 4; ++r)
        acc[r] += (double)Am[kk][ty + 8 * r] * (double)bv;
    }
    __syncthreads();
  }
#pragma unroll
  for (int r = 0; r < 4; ++r) {
    int m = m0 + ty + 8 * r, n = n0 + tx;
    C[(long long)m * Dn + n] = acc[r] * inv + ((m == n) ? 1e-5 : 0.0);
  }
}

// ---------------- f64 Cholesky + logdet (one block per 256x256 SPD) ----------
__global__ void cholesky_logdet_f64(double* __restrict__ mats, double* __restrict__ ld) {
  double* A = mats + (long long)blockIdx.x * Dn * Dn;
  int t = threadIdx.x;
  __shared__ double col[256];
  __shared__ double diag;
  __shared__ double lsum;
  if (t == 0) lsum = 0.0;
  __syncthreads();
  for (int k = 0; k < 256; ++k) {
    if (t == 0) {
      double dv = sqrt(fmax(A[k * 256 + k], 1e-300));
      diag = dv;
      lsum += log(dv);
    }
    __syncthreads();
    double ci = 0.0;
    if (t > k) {
      ci = A[t * 256 + k] / diag;
      col[t] = ci;
    }
    __syncthreads();
    if (t > k) {
      for (int j = k + 1; j <= t; ++j) A[t * 256 + j] -= ci * col[j];
    }
    __syncthreads();
  }
  if (t == 0) ld[blockIdx.x] = 2.0 * lsum;
}

__global__ void cov_final(const double* __restrict__ ld, float* __restrict__ outp) {
  outp[0] = (float)(-0.1 / (3.0 * 256.0) * (ld[0] + ld[1] + ld[2]));
}

// ---------------- output GEMM: ((x+h) @ out_w + b), transpose, de-norm -------
__global__ __launch_bounds__(256) void out_gemm(
    const float* __restrict__ X2, const float* __restrict__ H,
    const float* __restrict__ W, const float* __restrict__ bias,
    const float* __restrict__ stdev, const float* __restrict__ mean,
    float* __restrict__ out) {
  __shared__ float As[16][68];
  __shared__ float Bs[16][96];
  int t = threadIdx.x;
  int tx = t & 15, ty = t >> 4;
  int c0 = blockIdx.x * 64;
  int b = blockIdx.y;
  const float* x2 = X2 + (long long)b * Cn * Dn;
  const float* hh = H + (long long)b * Cn * Dn;
  float acc[4][6] = {};
  for (int k0 = 0; k0 < Dn; k0 += 16) {
    int mm = t >> 4, kk = t & 15;
#pragma unroll
    for (int r = 0; r < 4; ++r) {
      int m = mm + r * 16;
      long long idx = (long long)(c0 + m) * Dn + k0 + kk;
      As[kk][m] = x2[idx] + hh[idx];
    }
#pragma unroll
    for (int e = 0; e < 6; ++e) {
      int idx = t + e * 256;
      int bk = idx / 96, bn = idx % 96;
      Bs[bk][bn] = W[(k0 + bk) * Pn + bn];
    }
    __syncthreads();
#pragma unroll
    for (int k = 0; k < 16; ++k) {
      float a[4], bb[6];
#pragma unroll
      for (int i = 0; i < 4; ++i) a[i] = As[k][ty * 4 + i];
#pragma unroll
      for (int j = 0; j < 6; ++j) bb[j] = Bs[k][tx * 6 + j];
#pragma unroll
      for (int i = 0; i < 4; ++i)
#pragma unroll
        for (int j = 0; j < 6; ++j) acc[i][j] += a[i] * bb[j];
    }
    __syncthreads();
  }
#pragma unroll
  for (int i = 0; i < 4; ++i) {
    int c = c0 + ty * 4 + i;
    float sd = stdev[b * Cn + c];
    float mu = mean[b * Cn + c];
#pragma unroll
    for (int j = 0; j < 6; ++j) {
      int p = tx * 6 + j;
      float v = acc[i][j] + bias[p];
      out[((long long)(b * Pn + p)) * Cn + c] = v * sd + mu;
    }
  }
}

// =====================================================================
extern "C" void kernel_launch(void* const* d_in, const int* in_sizes, int n_in,
                              void* d_out, int out_size, void* d_ws, size_t ws_size,
                              hipStream_t stream) {
  (void)in_sizes; (void)n_in; (void)out_size; (void)ws_size;
  const float* x_enc = (const float*)d_in[0];
  const float* in_w = (const float*)d_in[4];
  const float* in_b = (const float*)d_in[5];
  const float* lq[3] = {(const float*)d_in[6], (const float*)d_in[7],
                        (const float*)d_in[8]};
  const float* down_w = (const float*)d_in[9];
  const float* down_b = (const float*)d_in[10];
  const float* down_ln = (const float*)d_in[11];
  const float* pred_w = (const float*)d_in[12];
  const float* pred_b = (const float*)d_in[13];
  const float* up_w = (const float*)d_in[14];
  const float* up_b = (const float*)d_in[15];
  const float* up_ln = (const float*)d_in[16];
  const float* out_w = (const float*)d_in[17];
  const float* out_b = (const float*)d_in[18];
  float* out = (float*)d_out;

  float* ws = (float*)d_ws;
  size_t off = 0;
  auto alloc = [&](size_t n) {
    float* p = ws + off;
    off += n;
    return p;
  };
  // keep offsets 8-byte aligned for the double regions
  float* mean = alloc((size_t)Bn * Cn);
  float* stdev = alloc((size_t)Bn * Cn);
  float* wsum = alloc(256);
  float* cmean = alloc(256);
  float* cistd = alloc(256);
  double* part = (double*)alloc(64 * 512 * 2);      // f64 partials
  double* ld = (double*)alloc(8);                   // 3 doubles (+pad)
  double* covd = (double*)alloc(3 * 65536 * 2);     // 3x 256x256 f64
  float* h = alloc((size_t)Bn * Cn * Dn);
  float* s1 = alloc((size_t)Bn * 512 * Dn);
  float* s2 = alloc((size_t)Bn * 128 * Dn);
  float* s3 = alloc((size_t)Bn * 32 * Dn);
  float* xp = alloc((size_t)Bn * 32 * Dn);
  float* xu0 = alloc((size_t)Bn * 128 * Dn);
  float* xu1 = alloc((size_t)Bn * 512 * Dn);
  float* qd = alloc((size_t)512 * Dn);
  float* qup = alloc((size_t)Bn * 2048 * Dn);   // also reused as o1 (otmp)
  float* kbuf = alloc((size_t)Bn * 2048 * Dn);  // also reused as o2
  float* vbuf = alloc((size_t)Bn * 2048 * Dn);  // also reused as final x (xu2)
  float* attn = alloc((size_t)Bn * 512 * 2048); // also reused as xc for cov
  float* xc = attn;
  float* otmp = qup;
  float* xu2 = vbuf;

  const float scale = 0.0625f;  // 1/sqrt(256)
  const float* np = nullptr;

  instnorm_stats<<<dim3(Cn / 256, Bn), 256, 0, stream>>>(x_enc, mean, stdev);
  wsum_kernel<<<1, 256, 0, stream>>>(in_w, wsum);

  // h = instance-norm fused input GEMM: [B, C, D]
  gemm_kernel<1, 0, 2><<<dim3(Dn / 64, Cn / 64, Bn), 256, 0, stream>>>(
      x_enc, in_w, h, in_b, Cn, Dn, Sn, Cn, Dn, Dn, (long long)Sn * Cn, 0,
      (long long)Cn * Dn, 0.f, mean, stdev, wsum);

  // ---------------- down layers ----------------
  int Ls[4] = {2048, 512, 128, 32};
  const float* xin = h;
  float* skips[3] = {s1, s2, s3};
  for (int i = 0; i < 3; ++i) {
    int L = Ls[i], Lq = Ls[i + 1];
    const float* Wq = down_w + (size_t)(i * 4 + 0) * 65536;
    const float* Wk = down_w + (size_t)(i * 4 + 1) * 65536;
    const float* Wv = down_w + (size_t)(i * 4 + 2) * 65536;
    const float* Wo = down_w + (size_t)(i * 4 + 3) * 65536;
    const float* bq = down_b + (i * 4 + 0) * 256;
    const float* bk = down_b + (i * 4 + 1) * 256;
    const float* bv = down_b + (i * 4 + 2) * 256;
    const float* bo = down_b + (i * 4 + 3) * 256;

    gemm_kernel<0, 0, 0><<<dim3(4, CDIV(Lq, 64), 1), 256, 0, stream>>>(
        lq[i], Wq, qd, bq, Lq, Dn, Dn, Dn, Dn, Dn, 0, 0, 0, 0.f, np, np, np);
    gemm_kernel<0, 0, 0><<<dim3(4, (Bn * L) / 64, 1), 256, 0, stream>>>(
        xin, Wk, kbuf, bk, Bn * L, Dn, Dn, Dn, Dn, Dn, 0, 0, 0, 0.f, np, np, np);
    gemm_kernel<0, 0, 0><<<dim3(4, (Bn * L) / 64, 1), 256, 0, stream>>>(
        xin, Wv, vbuf, bv, Bn * L, Dn, Dn, Dn, Dn, Dn, 0, 0, 0, 0.f, np, np, np);
    // scores [B, Lq, L] = scale * q @ k^T
    gemm_kernel<0, 1, 1><<<dim3(L / 64, CDIV(Lq, 64), Bn), 256, 0, stream>>>(
        qd, kbuf, attn, np, Lq, L, Dn, Dn, Dn, L, 0, (long long)L * Dn,
        (long long)Lq * L, scale, np, np, np);
    softmax_kernel<<<Bn * Lq, 256, 0, stream>>>(attn, L);
    // o1 = attn @ v
    gemm_kernel<0, 0, 0><<<dim3(4, CDIV(Lq, 64), Bn), 256, 0, stream>>>(
        attn, vbuf, otmp, np, Lq, Dn, L, L, Dn, Dn, (long long)Lq * L,
        (long long)L * Dn, (long long)Lq * Dn, 0.f, np, np, np);
    // o2 = o1 @ Wo + bo  (into kbuf, free after scores)
    gemm_kernel<0, 0, 0><<<dim3(4, (Bn * Lq) / 64, 1), 256, 0, stream>>>(
        otmp, Wo, kbuf, bo, Bn * Lq, Dn, Dn, Dn, Dn, Dn, 0, 0, 0, 0.f, np, np, np);
    ln_kernel<<<Bn * Lq, 256, 0, stream>>>(kbuf, nullptr, skips[i],
                                           down_ln + (i * 2 + 0) * 256,
                                           down_ln + (i * 2 + 1) * 256);
    xin = skips[i];
  }

  // ---------------- covariance loss (f64 Gram + f64 Cholesky) ----------------
  int nrs[3] = {Bn * 512, Bn * 128, Bn * 32};
  const float* sk[3] = {s1, s2, s3};
  for (int j = 0; j < 3; ++j) {
    int nr = nrs[j];
    colstat_partial<<<64, 256, 0, stream>>>(sk[j], part, nr);
    colstat_final<<<1, 256, 0, stream>>>(part, cmean, cistd, nr);
    xcnorm_kernel<<<1024, 256, 0, stream>>>(sk[j], xc, cmean, cistd,
                                            (long long)nr * Dn);
    cov_gemm_f64<<<dim3(8, 8, 1), 256, 0, stream>>>(
        xc, covd + (size_t)j * 65536, nr, 1.0 / (double)(nr - 1));
  }
  cholesky_logdet_f64<<<3, 256, 0, stream>>>(covd, ld);
  cov_final<<<1, 1, 0, stream>>>(ld, out + 6291456);

  // ---------------- pred head ----------------
  gemm_kernel<0, 0, 0><<<dim3(4, (Bn * 32) / 64, 1), 256, 0, stream>>>(
      s3, pred_w, xp, pred_b, Bn * 32, Dn, Dn, Dn, Dn, Dn, 0, 0, 0, 0.f, np, np, np);

  // ---------------- up layers ----------------
  int Lks[3] = {32, 128, 512}, Lqs[3] = {128, 512, 2048};
  const float* qins[3] = {s2, s1, h};
  const float* xins[3] = {xp, xu0, xu1};
  float* xouts[3] = {xu0, xu1, xu2};
  for (int i = 0; i < 3; ++i) {
    int Lk = Lks[i], Lq = Lqs[i];
    const float* Wq = up_w + (size_t)(i * 4 + 0) * 65536;
    const float* Wk = up_w + (size_t)(i * 4 + 1) * 65536;
    const float* Wv = up_w + (size_t)(i * 4 + 2) * 65536;
    const float* Wo = up_w + (size_t)(i * 4 + 3) * 65536;
    const float* bq = up_b + (i * 4 + 0) * 256;
    const float* bk = up_b + (i * 4 + 1) * 256;
    const float* bv = up_b + (i * 4 + 2) * 256;
    const float* bo = up_b + (i * 4 + 3) * 256;

    gemm_kernel<0, 0, 0><<<dim3(4, (Bn * Lq) / 64, 1), 256, 0, stream>>>(
        qins[i], Wq, qup, bq, Bn * Lq, Dn, Dn, Dn, Dn, Dn, 0, 0, 0, 0.f, np, np, np);
    gemm_kernel<0, 0, 0><<<dim3(4, (Bn * Lk) / 64, 1), 256, 0, stream>>>(
        xins[i], Wk, kbuf, bk, Bn * Lk, Dn, Dn, Dn, Dn, Dn, 0, 0, 0, 0.f, np, np, np);
    gemm_kernel<0, 0, 0><<<dim3(4, (Bn * Lk) / 64, 1), 256, 0, stream>>>(
        xins[i], Wv, vbuf, bv, Bn * Lk, Dn, Dn, Dn, Dn, Dn, 0, 0, 0, 0.f, np, np, np);
    // scores [B, Lq, Lk]
    gemm_kernel<0, 1, 1><<<dim3(CDIV(Lk, 64), Lq / 64, Bn), 256, 0, stream>>>(
        qup, kbuf, attn, np, Lq, Lk, Dn, Dn, Dn, Lk, (long long)Lq * Dn,
        (long long)Lk * Dn, (long long)Lq * Lk, scale, np, np, np);
    softmax_kernel<<<Bn * Lq, 256, 0, stream>>>(attn, Lk);
    // o1 = attn @ v (into qup region; q is consumed)
    gemm_kernel<0, 0, 0><<<dim3(4, CDIV(Lq, 64), Bn), 256, 0, stream>>>(
        attn, vbuf, otmp, np, Lq, Dn, Lk, Lk, Dn, Dn, (long long)Lq * Lk,
        (long long)Lk * Dn, (long long)Lq * Dn, 0.f, np, np, np);
    // o2 = o1 @ Wo + bo (into kbuf)
    gemm_kernel<0, 0, 0><<<dim3(4, (Bn * Lq) / 64, 1), 256, 0, stream>>>(
        otmp, Wo, kbuf, bo, Bn * Lq, Dn, Dn, Dn, Dn, Dn, 0, 0, 0, 0.f, np, np, np);
    // x = LN(o2 + qin)
    ln_kernel<<<Bn * Lq, 256, 0, stream>>>(kbuf, qins[i], xouts[i],
                                           up_ln + (i * 2 + 0) * 256,
                                           up_ln + (i * 2 + 1) * 256);
  }

  // ---------------- output projection + transpose + de-norm ----------------
  out_gemm<<<dim3(Cn / 64, Bn), 256, 0, stream>>>(xu2, h, out_w, out_b, stdev,
                                                  mean, out);
}

// Round 3
// 6798.833 us; speedup vs baseline: 1.2322x; 1.2322x over previous
//
#include <hip/hip_runtime.h>
#include <hip/hip_bf16.h>
#include <math.h>

#define CDIV(a, b) (((a) + (b) - 1) / (b))
typedef long long ll;

constexpr int Bn = 32;    // batch
constexpr int Sn = 720;   // seq len
constexpr int Cn = 2048;  // channels (tokens after transpose)
constexpr int Dn = 256;   // d_model
constexpr int Pn = 96;    // pred len

typedef __attribute__((ext_vector_type(8))) short bf16x8;
typedef __attribute__((ext_vector_type(4))) float f32x4;

// pack two f32 into two bf16 (RNE) in one u32 (a = low half)
__device__ inline unsigned pk2(float a, float b) {
  unsigned ua = __float_as_uint(a), ub = __float_as_uint(b);
  ua = (ua + 0x7fffu + ((ua >> 16) & 1u)) >> 16;
  ub = (ub + 0x7fffu + ((ub >> 16) & 1u)) >> 16;
  return (ua & 0xffffu) | ((ub & 0xffffu) << 16);
}

// ---------------- instance norm stats over time axis ----------------
__global__ void instnorm_stats(const float* __restrict__ x,
                               float* __restrict__ mean, float* __restrict__ stdev) {
  int c = blockIdx.x * 256 + threadIdx.x;
  int b = blockIdx.y;
  const float* p = x + (ll)b * Sn * Cn + c;
  float s = 0.f, q = 0.f;
  for (int t = 0; t < Sn; ++t) {
    float v = p[(ll)t * Cn];
    s += v; q += v * v;
  }
  float m = s / (float)Sn;
  float var = q / (float)Sn - m * m;
  var = fmaxf(var, 0.f);
  mean[b * Cn + c] = m;
  stdev[b * Cn + c] = sqrtf(var + 1e-5f);
}

__global__ void wsum_kernel(const float* __restrict__ w, float* __restrict__ ws) {
  int d = threadIdx.x;
  float s = 0.f;
  for (int t = 0; t < Sn; ++t) s += w[t * Dn + d];
  ws[d] = s;
}

// ---------------- bf16 MFMA GEMM ----------------
// C[m,n] = epi( sum_k opA(A)[m,k] * opB(B)[k,n] ), inputs f32 -> bf16 in staging.
// TRANSA=0: A row-major [M,K]. TRANSA=1: A stored [K,M] (lda = M-dim stride).
// TRANSB=0: B row-major [K,N]. TRANSB=1: B row-major [N,K].
// EPI: 0 = +bias(optional) ; 1 = *alpha ; 2 = instance-norm epilogue
// Tile 128x128, K-step 32, 4 waves (2x2 of 64x64), 16x16x32 bf16 MFMA.
template <int TRANSA, int TRANSB, int EPI>
__global__ __launch_bounds__(256) void mfma_gemm(
    const float* __restrict__ A, const float* __restrict__ Bm, float* __restrict__ Cc,
    const float* __restrict__ bias, int M, int N, int K, int lda, int ldb, int ldc,
    ll sA, ll sB, ll sC, float alpha,
    const float* __restrict__ aux0, const float* __restrict__ aux1,
    const float* __restrict__ aux2) {
  int g = blockIdx.z;
  A += (ll)g * sA;
  Bm += (ll)g * sB;
  Cc += (ll)g * sC;
  // [dim][k] bf16 tiles, padded to 40 shorts (80B row stride, 16B aligned)
  __shared__ short As[128][40];
  __shared__ short Bs[128][40];
  int t = threadIdx.x;
  int m0 = blockIdx.y * 128, n0 = blockIdx.x * 128;
  int w = t >> 6, lane = t & 63;
  int wm = (w >> 1) * 64, wn = (w & 1) * 64;
  int lrow = lane & 15;  // M-row (A) / N-col (B) within fragment
  int kq = lane >> 4;    // k-octet 0..3

  f32x4 acc[4][4] = {};

  for (int k0 = 0; k0 < K; k0 += 32) {
    // ---- stage A -> As[m][k] ----
    if (TRANSA == 0) {
#pragma unroll
      for (int e = 0; e < 8; ++e) {
        int idx = e * 256 + t;
        int kp = idx & 15, m = idx >> 4;
        int gm = m0 + m, gk = k0 + 2 * kp;
        float v0 = 0.f, v1 = 0.f;
        if (gm < M && gk < K) v0 = A[(ll)gm * lda + gk];
        if (gm < M && gk + 1 < K) v1 = A[(ll)gm * lda + gk + 1];
        *reinterpret_cast<unsigned*>(&As[m][2 * kp]) = pk2(v0, v1);
      }
    } else {
#pragma unroll
      for (int e = 0; e < 8; ++e) {
        int idx = e * 256 + t;
        int m = idx & 127, kp = idx >> 7;
        int gm = m0 + m, gk = k0 + 2 * kp;
        float v0 = 0.f, v1 = 0.f;
        if (gm < M && gk < K) v0 = A[(ll)gk * lda + gm];
        if (gm < M && gk + 1 < K) v1 = A[(ll)(gk + 1) * lda + gm];
        *reinterpret_cast<unsigned*>(&As[m][2 * kp]) = pk2(v0, v1);
      }
    }
    // ---- stage B -> Bs[n][k] ----
    if (TRANSB == 0) {
#pragma unroll
      for (int e = 0; e < 8; ++e) {
        int idx = e * 256 + t;
        int n = idx & 127, kp = idx >> 7;
        int gn = n0 + n, gk = k0 + 2 * kp;
        float v0 = 0.f, v1 = 0.f;
        if (gn < N && gk < K) v0 = Bm[(ll)gk * ldb + gn];
        if (gn < N && gk + 1 < K) v1 = Bm[(ll)(gk + 1) * ldb + gn];
        *reinterpret_cast<unsigned*>(&Bs[n][2 * kp]) = pk2(v0, v1);
      }
    } else {
#pragma unroll
      for (int e = 0; e < 8; ++e) {
        int idx = e * 256 + t;
        int kp = idx & 15, n = idx >> 4;
        int gn = n0 + n, gk = k0 + 2 * kp;
        float v0 = 0.f, v1 = 0.f;
        if (gn < N && gk < K) v0 = Bm[(ll)gn * ldb + gk];
        if (gn < N && gk + 1 < K) v1 = Bm[(ll)gn * ldb + gk + 1];
        *reinterpret_cast<unsigned*>(&Bs[n][2 * kp]) = pk2(v0, v1);
      }
    }
    __syncthreads();
    bf16x8 af[4], bfr[4];
#pragma unroll
    for (int i = 0; i < 4; ++i)
      af[i] = *reinterpret_cast<const bf16x8*>(&As[wm + i * 16 + lrow][kq * 8]);
#pragma unroll
    for (int j = 0; j < 4; ++j)
      bfr[j] = *reinterpret_cast<const bf16x8*>(&Bs[wn + j * 16 + lrow][kq * 8]);
#pragma unroll
    for (int i = 0; i < 4; ++i)
#pragma unroll
      for (int j = 0; j < 4; ++j)
        acc[i][j] = __builtin_amdgcn_mfma_f32_16x16x32_bf16(af[i], bfr[j],
                                                            acc[i][j], 0, 0, 0);
    __syncthreads();
  }

  // ---- epilogue: C/D layout col=lane&15, row=(lane>>4)*4+reg ----
#pragma unroll
  for (int i = 0; i < 4; ++i) {
#pragma unroll
    for (int j = 0; j < 4; ++j) {
      int c = n0 + wn + j * 16 + lrow;
      if (c >= N) continue;
#pragma unroll
      for (int reg = 0; reg < 4; ++reg) {
        int m = m0 + wm + i * 16 + kq * 4 + reg;
        if (m >= M) continue;
        float v = acc[i][j][reg];
        if (EPI == 0) {
          if (bias) v += bias[c];
        } else if (EPI == 1) {
          v *= alpha;
        } else if (EPI == 2) {
          float mu = aux0[(ll)g * M + m];
          float sd = aux1[(ll)g * M + m];
          v = (v - mu * aux2[c]) / sd + bias[c];
        }
        Cc[(ll)m * ldc + c] = v;
      }
    }
  }
}

// ---------------- block reduction helper (blockDim = 256) ----------------
__device__ inline float blk_reduce(float v, volatile float* sh, int op) {
  int lane = threadIdx.x & 63, w = threadIdx.x >> 6;
#pragma unroll
  for (int off = 32; off > 0; off >>= 1) {
    float o = __shfl_down(v, off, 64);
    v = op ? fmaxf(v, o) : (v + o);
  }
  __syncthreads();
  if (lane == 0) sh[w] = v;
  __syncthreads();
  float r = op ? fmaxf(fmaxf(sh[0], sh[1]), fmaxf(sh[2], sh[3]))
               : (sh[0] + sh[1] + sh[2] + sh[3]);
  return r;
}

// ---------------- row softmax (in place) ----------------
__global__ void softmax_kernel(float* __restrict__ S, int L) {
  __shared__ float sh[4];
  ll row = blockIdx.x;
  float* p = S + row * (ll)L;
  int t = threadIdx.x;
  float mx = -INFINITY;
  for (int i = t; i < L; i += 256) mx = fmaxf(mx, p[i]);
  mx = blk_reduce(mx, sh, 1);
  float sum = 0.f;
  for (int i = t; i < L; i += 256) {
    float e = __expf(p[i] - mx);
    p[i] = e;
    sum += e;
  }
  sum = blk_reduce(sum, sh, 0);
  float inv = 1.f / sum;
  for (int i = t; i < L; i += 256) p[i] *= inv;
}

// ---------------- LayerNorm over D=256, optional residual ----------------
__global__ void ln_kernel(const float* __restrict__ X, const float* __restrict__ RES,
                          float* __restrict__ Y, const float* __restrict__ gamma,
                          const float* __restrict__ beta) {
  __shared__ float sh[4];
  ll row = blockIdx.x;
  int t = threadIdx.x;
  float v = X[row * Dn + t];
  if (RES) v += RES[row * Dn + t];
  float m = blk_reduce(v, sh, 0) * (1.f / (float)Dn);
  float d = v - m;
  float var = blk_reduce(d * d, sh, 0) * (1.f / (float)Dn);
  Y[row * Dn + t] = d * rsqrtf(var + 1e-5f) * gamma[t] + beta[t];
}

// ---------------- covariance column stats (f64 partials) ----------------
__global__ void colstat_partial(const float* __restrict__ X, double* __restrict__ part,
                                int nrows) {
  int blk = blockIdx.x, t = threadIdx.x;
  int chunk = CDIV(nrows, 64);
  int r0 = blk * chunk, r1 = min(nrows, r0 + chunk);
  double s = 0.0, q = 0.0;
  for (int r = r0; r < r1; ++r) {
    double v = (double)X[(ll)r * Dn + t];
    s += v; q += v * v;
  }
  part[blk * 512 + t] = s;
  part[blk * 512 + 256 + t] = q;
}

__global__ void colstat_final(const double* __restrict__ part, float* __restrict__ cmean,
                              float* __restrict__ cistd, int nrows) {
  int t = threadIdx.x;
  double s = 0.0, q = 0.0;
  for (int b = 0; b < 64; ++b) {
    s += part[b * 512 + t];
    q += part[b * 512 + 256 + t];
  }
  double m = s / (double)nrows;
  double var = (q - (double)nrows * m * m) / (double)(nrows - 1);
  var = fmax(var, 0.0);
  cmean[t] = (float)m;
  cistd[t] = (float)(1.0 / (sqrt(var) + 1e-5));
}

__global__ void xcnorm_kernel(const float* __restrict__ X, float* __restrict__ XC,
                              const float* __restrict__ cmean,
                              const float* __restrict__ cistd, ll n) {
  for (ll i = blockIdx.x * 256LL + threadIdx.x; i < n; i += (ll)gridDim.x * 256) {
    int d = (int)(i & 255);
    XC[i] = (X[i] - cmean[d]) * cistd[d];
  }
}

// ---------------- cov Gram matrix with f64 accumulation ----------------
__global__ __launch_bounds__(256) void cov_gemm_f64(const float* __restrict__ XC,
                                                    double* __restrict__ C, int nr,
                                                    double inv) {
  __shared__ float Am[32][33];
  __shared__ float Bq[32][33];
  int t = threadIdx.x;
  int tx = t & 31, ty = t >> 5;
  int m0 = blockIdx.y * 32, n0 = blockIdx.x * 32;
  double acc[4] = {0.0, 0.0, 0.0, 0.0};
  for (int k0 = 0; k0 < nr; k0 += 32) {
#pragma unroll
    for (int e = 0; e < 4; ++e) {
      int idx = t + e * 256;
      int kk = idx >> 5, mm = idx & 31;
      Am[kk][mm] = XC[(ll)(k0 + kk) * Dn + m0 + mm];
      Bq[kk][mm] = XC[(ll)(k0 + kk) * Dn + n0 + mm];
    }
    __syncthreads();
#pragma unroll 8
    for (int kk = 0; kk < 32; ++kk) {
      float bv = Bq[kk][tx];
#pragma unroll
      for (int r = 0; r < 4; ++r)
        acc[r] += (double)Am[kk][ty + 8 * r] * (double)bv;
    }
    __syncthreads();
  }
#pragma unroll
  for (int r = 0; r < 4; ++r) {
    int m = m0 + ty + 8 * r, n = n0 + tx;
    C[(ll)m * Dn + n] = acc[r] * inv + ((m == n) ? 1e-5 : 0.0);
  }
}

// ---------------- blocked f64 Cholesky + logdet (1 block / matrix) ----------
__global__ __launch_bounds__(256) void cholesky_logdet_f64(double* __restrict__ mats,
                                                           double* __restrict__ ld) {
  double* A = mats + (ll)blockIdx.x * Dn * Dn;
  int t = threadIdx.x;
  __shared__ double D[32][33];
  __shared__ double Lc[32][33];
  __shared__ double dsh[32];
  __shared__ double dinv[32];
  double lsum = 0.0;  // thread 0 accumulates
  for (int kb = 0; kb < Dn / 32; ++kb) {
    int d0 = kb * 32;
    // load diagonal block (lower part used)
    for (int e = t; e < 1024; e += 256) {
      int i = e >> 5, j = e & 31;
      D[i][j] = A[(ll)(d0 + i) * Dn + d0 + j];
    }
    __syncthreads();
    // factor D = L11 L11^T (unscaled-column variant: 2 barriers/step)
    for (int k = 0; k < 32; ++k) {
      if (t == 0) {
        double dk = sqrt(fmax(D[k][k], 1e-300));
        dsh[k] = dk;
        dinv[k] = 1.0 / (dk * dk);
      }
      __syncthreads();
      double inv = dinv[k];
      for (int e = t; e < 1024; e += 256) {
        int i = e >> 5, j = e & 31;
        if (i > k && j > k && j <= i) D[i][j] -= D[i][k] * D[j][k] * inv;
      }
      __syncthreads();
    }
    // scale columns to true L11
    for (int e = t; e < 1024; e += 256) {
      int i = e >> 5, j = e & 31;
      if (i > j) D[i][j] /= dsh[j];
      else if (i == j) D[i][j] = dsh[i];
    }
    __syncthreads();
    // logdet contribution
    if (t < 32) {
      double lg = log(dsh[t]);
#pragma unroll
      for (int off = 16; off > 0; off >>= 1) lg += __shfl_down(lg, off, 64);
      if (t == 0) lsum += 2.0 * lg;
    }
    // L21: each thread solves one trailing row (forward substitution)
    int r = d0 + 32 + t;
    bool act = (r < Dn);
    double x[32];
    if (act) {
#pragma unroll
      for (int j = 0; j < 32; ++j) x[j] = A[(ll)r * Dn + d0 + j];
#pragma unroll
      for (int j = 0; j < 32; ++j) {
        double s = x[j];
#pragma unroll
        for (int i = 0; i < j; ++i) s -= x[i] * D[j][i];
        x[j] = s / D[j][j];
      }
#pragma unroll
      for (int j = 0; j < 32; ++j) A[(ll)r * Dn + d0 + j] = x[j];
    }
    __syncthreads();
    // trailing update: A22 -= L21 L21^T (lower triangle only)
    int ntrail = Dn - d0 - 32;
    for (int cc = 0; cc < ntrail; cc += 32) {
      for (int e = t; e < 1024; e += 256) {
        int i = e >> 5, j = e & 31;
        if (cc + i < ntrail) Lc[i][j] = A[(ll)(d0 + 32 + cc + i) * Dn + d0 + j];
      }
      __syncthreads();
      if (act) {
        int cend = min(cc + 32, r - d0 - 32 + 1);
        for (int ci = cc; ci < cend; ++ci) {
          double s = 0.0;
#pragma unroll
          for (int k2 = 0; k2 < 32; ++k2) s += x[k2] * Lc[ci - cc][k2];
          A[(ll)r * Dn + d0 + 32 + ci] -= s;
        }
      }
      __syncthreads();
    }
  }
  if (t == 0) ld[blockIdx.x] = lsum;
}

__global__ void cov_final(const double* __restrict__ ld, float* __restrict__ outp) {
  outp[0] = (float)(-0.1 / (3.0 * 256.0) * (ld[0] + ld[1] + ld[2]));
}

// ---------------- output GEMM: ((x+h) @ out_w + b), transpose, de-norm -------
__global__ __launch_bounds__(256) void out_gemm(
    const float* __restrict__ X2, const float* __restrict__ H,
    const float* __restrict__ W, const float* __restrict__ bias,
    const float* __restrict__ stdev, const float* __restrict__ mean,
    float* __restrict__ out) {
  __shared__ float As[16][68];
  __shared__ float Bs[16][96];
  int t = threadIdx.x;
  int tx = t & 15, ty = t >> 4;
  int c0 = blockIdx.x * 64;
  int b = blockIdx.y;
  const float* x2 = X2 + (ll)b * Cn * Dn;
  const float* hh = H + (ll)b * Cn * Dn;
  float acc[4][6] = {};
  for (int k0 = 0; k0 < Dn; k0 += 16) {
    int mm = t >> 4, kk = t & 15;
#pragma unroll
    for (int r = 0; r < 4; ++r) {
      int m = mm + r * 16;
      ll idx = (ll)(c0 + m) * Dn + k0 + kk;
      As[kk][m] = x2[idx] + hh[idx];
    }
#pragma unroll
    for (int e = 0; e < 6; ++e) {
      int idx = t + e * 256;
      int bk = idx / 96, bn = idx % 96;
      Bs[bk][bn] = W[(k0 + bk) * Pn + bn];
    }
    __syncthreads();
#pragma unroll
    for (int k = 0; k < 16; ++k) {
      float a[4], bb[6];
#pragma unroll
      for (int i = 0; i < 4; ++i) a[i] = As[k][ty * 4 + i];
#pragma unroll
      for (int j = 0; j < 6; ++j) bb[j] = Bs[k][tx * 6 + j];
#pragma unroll
      for (int i = 0; i < 4; ++i)
#pragma unroll
        for (int j = 0; j < 6; ++j) acc[i][j] += a[i] * bb[j];
    }
    __syncthreads();
  }
#pragma unroll
  for (int i = 0; i < 4; ++i) {
    int c = c0 + ty * 4 + i;
    float sd = stdev[b * Cn + c];
    float mu = mean[b * Cn + c];
#pragma unroll
    for (int j = 0; j < 6; ++j) {
      int p = tx * 6 + j;
      float v = acc[i][j] + bias[p];
      out[((ll)(b * Pn + p)) * Cn + c] = v * sd + mu;
    }
  }
}

// =====================================================================
extern "C" void kernel_launch(void* const* d_in, const int* in_sizes, int n_in,
                              void* d_out, int out_size, void* d_ws, size_t ws_size,
                              hipStream_t stream) {
  (void)in_sizes; (void)n_in; (void)out_size; (void)ws_size;
  const float* x_enc = (const float*)d_in[0];
  const float* in_w = (const float*)d_in[4];
  const float* in_b = (const float*)d_in[5];
  const float* lq[3] = {(const float*)d_in[6], (const float*)d_in[7],
                        (const float*)d_in[8]};
  const float* down_w = (const float*)d_in[9];
  const float* down_b = (const float*)d_in[10];
  const float* down_ln = (const float*)d_in[11];
  const float* pred_w = (const float*)d_in[12];
  const float* pred_b = (const float*)d_in[13];
  const float* up_w = (const float*)d_in[14];
  const float* up_b = (const float*)d_in[15];
  const float* up_ln = (const float*)d_in[16];
  const float* out_w = (const float*)d_in[17];
  const float* out_b = (const float*)d_in[18];
  float* out = (float*)d_out;

  float* ws = (float*)d_ws;
  size_t off = 0;
  auto alloc = [&](size_t n) {
    float* p = ws + off;
    off += n;
    return p;
  };
  float* mean = alloc((size_t)Bn * Cn);
  float* stdev = alloc((size_t)Bn * Cn);
  float* wsum = alloc(256);
  float* cmean = alloc(256);
  float* cistd = alloc(256);
  double* part = (double*)alloc(64 * 512 * 2);
  double* ld = (double*)alloc(8);
  double* covd = (double*)alloc(3 * 65536 * 2);
  float* h = alloc((size_t)Bn * Cn * Dn);
  float* s1 = alloc((size_t)Bn * 512 * Dn);
  float* s2 = alloc((size_t)Bn * 128 * Dn);
  float* s3 = alloc((size_t)Bn * 32 * Dn);
  float* xp = alloc((size_t)Bn * 32 * Dn);
  float* xu0 = alloc((size_t)Bn * 128 * Dn);
  float* xu1 = alloc((size_t)Bn * 512 * Dn);
  float* qd = alloc((size_t)512 * Dn);
  float* qup = alloc((size_t)Bn * 2048 * Dn);   // also reused as o1 (otmp)
  float* kbuf = alloc((size_t)Bn * 2048 * Dn);  // also reused as o2
  float* vbuf = alloc((size_t)Bn * 2048 * Dn);  // also reused as final x (xu2)
  float* attn = alloc((size_t)Bn * 512 * 2048); // also reused as xc for cov
  float* xc = attn;
  float* otmp = qup;
  float* xu2 = vbuf;

  const float scale = 0.0625f;  // 1/sqrt(256)
  const float* np = nullptr;

  instnorm_stats<<<dim3(Cn / 256, Bn), 256, 0, stream>>>(x_enc, mean, stdev);
  wsum_kernel<<<1, 256, 0, stream>>>(in_w, wsum);

  // h = instance-norm fused input GEMM: [B, C, D]
  mfma_gemm<1, 0, 2><<<dim3(2, 16, Bn), 256, 0, stream>>>(
      x_enc, in_w, h, in_b, Cn, Dn, Sn, Cn, Dn, Dn, (ll)Sn * Cn, 0,
      (ll)Cn * Dn, 0.f, mean, stdev, wsum);

  // ---------------- down layers ----------------
  int Ls[4] = {2048, 512, 128, 32};
  const float* xin = h;
  float* skips[3] = {s1, s2, s3};
  for (int i = 0; i < 3; ++i) {
    int L = Ls[i], Lq = Ls[i + 1];
    const float* Wq = down_w + (size_t)(i * 4 + 0) * 65536;
    const float* Wk = down_w + (size_t)(i * 4 + 1) * 65536;
    const float* Wv = down_w + (size_t)(i * 4 + 2) * 65536;
    const float* Wo = down_w + (size_t)(i * 4 + 3) * 65536;
    const float* bq = down_b + (i * 4 + 0) * 256;
    const float* bk = down_b + (i * 4 + 1) * 256;
    const float* bv = down_b + (i * 4 + 2) * 256;
    const float* bo = down_b + (i * 4 + 3) * 256;

    mfma_gemm<0, 0, 0><<<dim3(2, CDIV(Lq, 128), 1), 256, 0, stream>>>(
        lq[i], Wq, qd, bq, Lq, Dn, Dn, Dn, Dn, Dn, 0, 0, 0, 0.f, np, np, np);
    mfma_gemm<0, 0, 0><<<dim3(2, CDIV(Bn * L, 128), 1), 256, 0, stream>>>(
        xin, Wk, kbuf, bk, Bn * L, Dn, Dn, Dn, Dn, Dn, 0, 0, 0, 0.f, np, np, np);
    mfma_gemm<0, 0, 0><<<dim3(2, CDIV(Bn * L, 128), 1), 256, 0, stream>>>(
        xin, Wv, vbuf, bv, Bn * L, Dn, Dn, Dn, Dn, Dn, 0, 0, 0, 0.f, np, np, np);
    // scores [B, Lq, L] = scale * q @ k^T   (q shared over batch: sA=0)
    mfma_gemm<0, 1, 1><<<dim3(CDIV(L, 128), CDIV(Lq, 128), Bn), 256, 0, stream>>>(
        qd, kbuf, attn, np, Lq, L, Dn, Dn, Dn, L, 0, (ll)L * Dn,
        (ll)Lq * L, scale, np, np, np);
    softmax_kernel<<<Bn * Lq, 256, 0, stream>>>(attn, L);
    // o1 = attn @ v
    mfma_gemm<0, 0, 0><<<dim3(2, CDIV(Lq, 128), Bn), 256, 0, stream>>>(
        attn, vbuf, otmp, np, Lq, Dn, L, L, Dn, Dn, (ll)Lq * L,
        (ll)L * Dn, (ll)Lq * Dn, 0.f, np, np, np);
    // o2 = o1 @ Wo + bo
    mfma_gemm<0, 0, 0><<<dim3(2, CDIV(Bn * Lq, 128), 1), 256, 0, stream>>>(
        otmp, Wo, kbuf, bo, Bn * Lq, Dn, Dn, Dn, Dn, Dn, 0, 0, 0, 0.f, np, np, np);
    ln_kernel<<<Bn * Lq, 256, 0, stream>>>(kbuf, nullptr, skips[i],
                                           down_ln + (i * 2 + 0) * 256,
                                           down_ln + (i * 2 + 1) * 256);
    xin = skips[i];
  }

  // ---------------- covariance loss (f64 Gram + blocked f64 Cholesky) --------
  int nrs[3] = {Bn * 512, Bn * 128, Bn * 32};
  const float* sk[3] = {s1, s2, s3};
  for (int j = 0; j < 3; ++j) {
    int nr = nrs[j];
    colstat_partial<<<64, 256, 0, stream>>>(sk[j], part, nr);
    colstat_final<<<1, 256, 0, stream>>>(part, cmean, cistd, nr);
    xcnorm_kernel<<<1024, 256, 0, stream>>>(sk[j], xc, cmean, cistd,
                                            (ll)nr * Dn);
    cov_gemm_f64<<<dim3(8, 8, 1), 256, 0, stream>>>(
        xc, covd + (size_t)j * 65536, nr, 1.0 / (double)(nr - 1));
  }
  cholesky_logdet_f64<<<3, 256, 0, stream>>>(covd, ld);
  cov_final<<<1, 1, 0, stream>>>(ld, out + 6291456);

  // ---------------- pred head ----------------
  mfma_gemm<0, 0, 0><<<dim3(2, CDIV(Bn * 32, 128), 1), 256, 0, stream>>>(
      s3, pred_w, xp, pred_b, Bn * 32, Dn, Dn, Dn, Dn, Dn, 0, 0, 0, 0.f, np, np, np);

  // ---------------- up layers ----------------
  int Lks[3] = {32, 128, 512}, Lqs[3] = {128, 512, 2048};
  const float* qins[3] = {s2, s1, h};
  const float* xins[3] = {xp, xu0, xu1};
  float* xouts[3] = {xu0, xu1, xu2};
  for (int i = 0; i < 3; ++i) {
    int Lk = Lks[i], Lq = Lqs[i];
    const float* Wq = up_w + (size_t)(i * 4 + 0) * 65536;
    const float* Wk = up_w + (size_t)(i * 4 + 1) * 65536;
    const float* Wv = up_w + (size_t)(i * 4 + 2) * 65536;
    const float* Wo = up_w + (size_t)(i * 4 + 3) * 65536;
    const float* bq = up_b + (i * 4 + 0) * 256;
    const float* bk = up_b + (i * 4 + 1) * 256;
    const float* bv = up_b + (i * 4 + 2) * 256;
    const float* bo = up_b + (i * 4 + 3) * 256;

    mfma_gemm<0, 0, 0><<<dim3(2, CDIV(Bn * Lq, 128), 1), 256, 0, stream>>>(
        qins[i], Wq, qup, bq, Bn * Lq, Dn, Dn, Dn, Dn, Dn, 0, 0, 0, 0.f, np, np, np);
    mfma_gemm<0, 0, 0><<<dim3(2, CDIV(Bn * Lk, 128), 1), 256, 0, stream>>>(
        xins[i], Wk, kbuf, bk, Bn * Lk, Dn, Dn, Dn, Dn, Dn, 0, 0, 0, 0.f, np, np, np);
    mfma_gemm<0, 0, 0><<<dim3(2, CDIV(Bn * Lk, 128), 1), 256, 0, stream>>>(
        xins[i], Wv, vbuf, bv, Bn * Lk, Dn, Dn, Dn, Dn, Dn, 0, 0, 0, 0.f, np, np, np);
    // scores [B, Lq, Lk]
    mfma_gemm<0, 1, 1><<<dim3(CDIV(Lk, 128), CDIV(Lq, 128), Bn), 256, 0, stream>>>(
        qup, kbuf, attn, np, Lq, Lk, Dn, Dn, Dn, Lk, (ll)Lq * Dn,
        (ll)Lk * Dn, (ll)Lq * Lk, scale, np, np, np);
    softmax_kernel<<<Bn * Lq, 256, 0, stream>>>(attn, Lk);
    // o1 = attn @ v
    mfma_gemm<0, 0, 0><<<dim3(2, CDIV(Lq, 128), Bn), 256, 0, stream>>>(
        attn, vbuf, otmp, np, Lq, Dn, Lk, Lk, Dn, Dn, (ll)Lq * Lk,
        (ll)Lk * Dn, (ll)Lq * Dn, 0.f, np, np, np);
    // o2 = o1 @ Wo + bo
    mfma_gemm<0, 0, 0><<<dim3(2, CDIV(Bn * Lq, 128), 1), 256, 0, stream>>>(
        otmp, Wo, kbuf, bo, Bn * Lq, Dn, Dn, Dn, Dn, Dn, 0, 0, 0, 0.f, np, np, np);
    // x = LN(o2 + qin)
    ln_kernel<<<Bn * Lq, 256, 0, stream>>>(kbuf, qins[i], xouts[i],
                                           up_ln + (i * 2 + 0) * 256,
                                           up_ln + (i * 2 + 1) * 256);
  }

  // ---------------- output projection + transpose + de-norm ----------------
  out_gemm<<<dim3(Cn / 64, Bn), 256, 0, stream>>>(xu2, h, out_w, out_b, stdev,
                                                  mean, out);
}

// Round 4
// 2490.056 us; speedup vs baseline: 3.3643x; 2.7304x over previous
//
#include <hip/hip_runtime.h>
#include <hip/hip_bf16.h>
#include <math.h>

#define CDIV(a, b) (((a) + (b) - 1) / (b))
typedef long long ll;
typedef unsigned short ushort_t;

constexpr int Bn = 32;    // batch
constexpr int Sn = 720;   // seq len
constexpr int Cn = 2048;  // channels (tokens after transpose)
constexpr int Dn = 256;   // d_model
constexpr int Pn = 96;    // pred len

typedef __attribute__((ext_vector_type(8))) short bf16x8;
typedef __attribute__((ext_vector_type(4))) float f32x4;

__device__ inline ushort_t rne1(float x) {
  unsigned u = __float_as_uint(x);
  u = (u + 0x7fffu + ((u >> 16) & 1u)) >> 16;
  return (ushort_t)u;
}
__device__ inline float b2f(ushort_t u) { return __uint_as_float(((unsigned)u) << 16); }

// ---------------- instance norm stats over time axis ----------------
__global__ void instnorm_stats(const float* __restrict__ x,
                               float* __restrict__ mean, float* __restrict__ stdev) {
  int c = blockIdx.x * 256 + threadIdx.x;
  int b = blockIdx.y;
  const float* p = x + (ll)b * Sn * Cn + c;
  float s = 0.f, q = 0.f;
  for (int t = 0; t < Sn; ++t) {
    float v = p[(ll)t * Cn];
    s += v; q += v * v;
  }
  float m = s / (float)Sn;
  float var = q / (float)Sn - m * m;
  var = fmaxf(var, 0.f);
  mean[b * Cn + c] = m;
  stdev[b * Cn + c] = sqrtf(var + 1e-5f);
}

// ---------------- normalize + transpose: x[b][s][c] -> xnT[b][c][s] bf16 ------
__global__ void normT_kernel(const float* __restrict__ X, ushort_t* __restrict__ D,
                             const float* __restrict__ mean,
                             const float* __restrict__ stdev) {
  int b = blockIdx.z;
  __shared__ float tl[32][33];
  int t = threadIdx.x;
  int tx = t & 31, ty = t >> 5;
  int s0 = blockIdx.y * 32, c0 = blockIdx.x * 32;
#pragma unroll
  for (int e = 0; e < 4; ++e) {
    int s = s0 + ty + 8 * e;
    tl[ty + 8 * e][tx] = (s < Sn) ? X[((ll)b * Sn + s) * Cn + c0 + tx] : 0.f;
  }
  __syncthreads();
#pragma unroll
  for (int e = 0; e < 4; ++e) {
    int c = c0 + ty + 8 * e, s = s0 + tx;
    if (s < Sn) {
      float mu = mean[b * Cn + c], sd = stdev[b * Cn + c];
      D[((ll)b * Cn + c) * Sn + s] = rne1((tl[tx][ty + 8 * e] - mu) / sd);
    }
  }
}

// ---------------- transpose-convert: W[K][N] f32 -> WT[N][K] bf16 -------------
__global__ void cvtT_kernel(const float* __restrict__ S, ushort_t* __restrict__ D,
                            int K, int N) {
  int z = blockIdx.z;
  S += (ll)z * K * N;
  D += (ll)z * N * K;
  __shared__ float tl[32][33];
  int t = threadIdx.x;
  int tx = t & 31, ty = t >> 5;
  int k0 = blockIdx.y * 32, n0 = blockIdx.x * 32;
#pragma unroll
  for (int e = 0; e < 4; ++e) {
    int k = k0 + ty + 8 * e;
    tl[ty + 8 * e][tx] = (k < K && n0 + tx < N) ? S[(ll)k * N + n0 + tx] : 0.f;
  }
  __syncthreads();
#pragma unroll
  for (int e = 0; e < 4; ++e) {
    int n = n0 + ty + 8 * e, kk = k0 + tx;
    if (n < N && kk < K) D[(ll)n * K + kk] = rne1(tl[tx][ty + 8 * e]);
  }
}

__global__ void cvt_bf(const float* __restrict__ S, ushort_t* __restrict__ D, int n) {
  int i = blockIdx.x * 256 + threadIdx.x;
  if (i < n) D[i] = rne1(S[i]);
}

// ---------------- canonical bf16 MFMA GEMM: C = A[M][K] * B[N][K]^T ----------
// MODE bits: 1 = write f32 C (ldcf), 2 = write bf16 C (ldcb), 4 = write bf16 C^T
// v = acc*alpha + bias[c]
template <int MODE>
__global__ __launch_bounds__(256) void gemm_bf(
    const ushort_t* __restrict__ A, const ushort_t* __restrict__ B,
    int M, int N, int K, int lda, int ldb, ll sA, ll sB,
    const float* __restrict__ bias, float alpha,
    float* __restrict__ Cf, int ldcf, ll sCf,
    ushort_t* __restrict__ Cb, int ldcb, ll sCb) {
  int g = blockIdx.z;
  A += (ll)g * sA;
  B += (ll)g * sB;
  if (MODE & 1) Cf += (ll)g * sCf;
  if (MODE & 6) Cb += (ll)g * sCb;
  __shared__ ushort_t As[128][40];
  __shared__ ushort_t Bs[128][40];
  int t = threadIdx.x;
  int m0 = blockIdx.y * 128, n0 = blockIdx.x * 128;
  int w = t >> 6, lane = t & 63;
  int wm = (w >> 1) * 64, wn = (w & 1) * 64;
  int lrow = lane & 15, kq = lane >> 4;
  int r0 = t >> 2, kc = (t & 3) * 8;
  f32x4 acc[4][4] = {};
  for (int k0 = 0; k0 < K; k0 += 32) {
    bf16x8 z8 = {};
#pragma unroll
    for (int e = 0; e < 2; ++e) {
      int row = e * 64 + r0;
      bf16x8 va = z8, vb = z8;
      if (m0 + row < M && k0 + kc < K)
        va = *reinterpret_cast<const bf16x8*>(&A[(ll)(m0 + row) * lda + k0 + kc]);
      if (n0 + row < N && k0 + kc < K)
        vb = *reinterpret_cast<const bf16x8*>(&B[(ll)(n0 + row) * ldb + k0 + kc]);
      *reinterpret_cast<bf16x8*>(&As[row][kc]) = va;
      *reinterpret_cast<bf16x8*>(&Bs[row][kc]) = vb;
    }
    __syncthreads();
    bf16x8 af[4], bfr[4];
#pragma unroll
    for (int i = 0; i < 4; ++i)
      af[i] = *reinterpret_cast<const bf16x8*>(&As[wm + i * 16 + lrow][kq * 8]);
#pragma unroll
    for (int j = 0; j < 4; ++j)
      bfr[j] = *reinterpret_cast<const bf16x8*>(&Bs[wn + j * 16 + lrow][kq * 8]);
#pragma unroll
    for (int i = 0; i < 4; ++i)
#pragma unroll
      for (int j = 0; j < 4; ++j)
        acc[i][j] = __builtin_amdgcn_mfma_f32_16x16x32_bf16(af[i], bfr[j],
                                                            acc[i][j], 0, 0, 0);
    __syncthreads();
  }
#pragma unroll
  for (int i = 0; i < 4; ++i) {
    int mb = m0 + wm + i * 16 + kq * 4;
    if (mb >= M) continue;
#pragma unroll
    for (int j = 0; j < 4; ++j) {
      int c = n0 + wn + j * 16 + lrow;
      if (c >= N) continue;
      float bv = bias ? bias[c] : 0.f;
#pragma unroll
      for (int reg = 0; reg < 4; ++reg) {
        int m = mb + reg;
        float v = acc[i][j][reg] * alpha + bv;
        if (MODE & 1) Cf[(ll)m * ldcf + c] = v;
        if (MODE & 2) Cb[(ll)m * ldcb + c] = rne1(v);
        if (MODE & 4) Cb[(ll)c * ldcb + m] = rne1(v);
      }
    }
  }
}

// ---------------- block reduction helper (blockDim = 256) ----------------
__device__ inline float blk_reduce(float v, volatile float* sh, int op) {
  int lane = threadIdx.x & 63, w = threadIdx.x >> 6;
#pragma unroll
  for (int off = 32; off > 0; off >>= 1) {
    float o = __shfl_down(v, off, 64);
    v = op ? fmaxf(v, o) : (v + o);
  }
  __syncthreads();
  if (lane == 0) sh[w] = v;
  __syncthreads();
  float r = op ? fmaxf(fmaxf(sh[0], sh[1]), fmaxf(sh[2], sh[3]))
               : (sh[0] + sh[1] + sh[2] + sh[3]);
  return r;
}

// ---------------- row softmax: f32 scores in, bf16 probs out ----------------
template <int LL>
__global__ void softmax_bf(const float* __restrict__ S, ushort_t* __restrict__ P) {
  constexpr int NE = (LL + 255) / 256;
  __shared__ float sh[4];
  ll row = blockIdx.x;
  const float* p = S + row * (ll)LL;
  ushort_t* q = P + row * (ll)LL;
  int t = threadIdx.x;
  float e[NE];
  float mx = -INFINITY;
#pragma unroll
  for (int k = 0; k < NE; ++k) {
    int i = t + k * 256;
    if (i < LL) { e[k] = p[i]; mx = fmaxf(mx, e[k]); }
  }
  mx = blk_reduce(mx, sh, 1);
  float sum = 0.f;
#pragma unroll
  for (int k = 0; k < NE; ++k) {
    int i = t + k * 256;
    if (i < LL) { e[k] = __expf(e[k] - mx); sum += e[k]; }
  }
  sum = blk_reduce(sum, sh, 0);
  float inv = 1.f / sum;
#pragma unroll
  for (int k = 0; k < NE; ++k) {
    int i = t + k * 256;
    if (i < LL) q[i] = rne1(e[k] * inv);
  }
}

// ---------------- LayerNorm over D=256; optional bf16 residual ----------------
// Y = LN(X + RESb); writes f32 Yf (opt) and bf16 Yb (opt, + RES if postadd)
__global__ void ln_kernel(const float* __restrict__ X, const ushort_t* __restrict__ RESb,
                          float* __restrict__ Yf, ushort_t* __restrict__ Yb, int postadd,
                          const float* __restrict__ gamma, const float* __restrict__ beta) {
  __shared__ float sh[4];
  ll row = blockIdx.x;
  int t = threadIdx.x;
  float r = RESb ? b2f(RESb[row * Dn + t]) : 0.f;
  float v = X[row * Dn + t] + r;
  float m = blk_reduce(v, sh, 0) * (1.f / (float)Dn);
  float d = v - m;
  float var = blk_reduce(d * d, sh, 0) * (1.f / (float)Dn);
  float y = d * rsqrtf(var + 1e-5f) * gamma[t] + beta[t];
  if (Yf) Yf[row * Dn + t] = y;
  if (Yb) Yb[row * Dn + t] = rne1(y + (postadd ? r : 0.f));
}

// ---------------- covariance column stats (f64 partials) ----------------
__global__ void colstat_partial(const float* __restrict__ X, double* __restrict__ part,
                                int nrows) {
  int blk = blockIdx.x, t = threadIdx.x;
  int chunk = CDIV(nrows, 64);
  int r0 = blk * chunk, r1 = min(nrows, r0 + chunk);
  double s = 0.0, q = 0.0;
  for (int r = r0; r < r1; ++r) {
    double v = (double)X[(ll)r * Dn + t];
    s += v; q += v * v;
  }
  part[blk * 512 + t] = s;
  part[blk * 512 + 256 + t] = q;
}

__global__ void colstat_final(const double* __restrict__ part, float* __restrict__ cmean,
                              float* __restrict__ cistd, int nrows) {
  int t = threadIdx.x;
  double s = 0.0, q = 0.0;
  for (int b = 0; b < 64; ++b) {
    s += part[b * 512 + t];
    q += part[b * 512 + 256 + t];
  }
  double m = s / (double)nrows;
  double var = (q - (double)nrows * m * m) / (double)(nrows - 1);
  var = fmax(var, 0.0);
  cmean[t] = (float)m;
  cistd[t] = (float)(1.0 / (sqrt(var) + 1e-5));
}

__global__ void xcnorm_kernel(const float* __restrict__ X, float* __restrict__ XC,
                              const float* __restrict__ cmean,
                              const float* __restrict__ cistd, ll n) {
  for (ll i = blockIdx.x * 256LL + threadIdx.x; i < n; i += (ll)gridDim.x * 256) {
    int d = (int)(i & 255);
    XC[i] = (X[i] - cmean[d]) * cistd[d];
  }
}

// ---------------- split-K cov Gram, f64 partials ----------------
__global__ __launch_bounds__(256) void cov_gemm_f64_split(const float* __restrict__ XC,
                                                          double* __restrict__ part,
                                                          int nr) {
  __shared__ float Am[32][33];
  __shared__ float Bq[32][33];
  int t = threadIdx.x;
  int tx = t & 31, ty = t >> 5;
  int m0 = blockIdx.y * 32, n0 = blockIdx.x * 32;
  int z = blockIdx.z;
  int chunk = nr >> 4;
  int kbeg = z * chunk, kend = kbeg + chunk;
  double acc[4] = {0.0, 0.0, 0.0, 0.0};
  for (int k0 = kbeg; k0 < kend; k0 += 32) {
#pragma unroll
    for (int e = 0; e < 4; ++e) {
      int idx = t + e * 256;
      int kk = idx >> 5, mm = idx & 31;
      Am[kk][mm] = XC[(ll)(k0 + kk) * Dn + m0 + mm];
      Bq[kk][mm] = XC[(ll)(k0 + kk) * Dn + n0 + mm];
    }
    __syncthreads();
#pragma unroll 8
    for (int kk = 0; kk < 32; ++kk) {
      float bv = Bq[kk][tx];
#pragma unroll
      for (int r = 0; r < 4; ++r)
        acc[r] += (double)Am[kk][ty + 8 * r] * (double)bv;
    }
    __syncthreads();
  }
#pragma unroll
  for (int r = 0; r < 4; ++r) {
    int m = m0 + ty + 8 * r, n = n0 + tx;
    part[(ll)z * 65536 + m * 256 + n] = acc[r];
  }
}

__global__ void cov_reduce(const double* __restrict__ part, double* __restrict__ Cd,
                           double inv) {
  int idx = blockIdx.x * 256 + threadIdx.x;
  double s = 0.0;
#pragma unroll
  for (int z = 0; z < 16; ++z) s += part[(ll)z * 65536 + idx];
  int m = idx >> 8, n = idx & 255;
  Cd[idx] = s * inv + ((m == n) ? 1e-5 : 0.0);
}

// ---------------- blocked f64 Cholesky + logdet (1 block / matrix) ----------
__global__ __launch_bounds__(256) void cholesky_logdet_f64(double* __restrict__ mats,
                                                           double* __restrict__ ld) {
  double* A = mats + (ll)blockIdx.x * Dn * Dn;
  int t = threadIdx.x;
  __shared__ double D[32][33];
  __shared__ double Lc[32][33];
  __shared__ double dsh[32];
  __shared__ double dinv[32];
  double lsum = 0.0;
  for (int kb = 0; kb < Dn / 32; ++kb) {
    int d0 = kb * 32;
    for (int e = t; e < 1024; e += 256) {
      int i = e >> 5, j = e & 31;
      D[i][j] = A[(ll)(d0 + i) * Dn + d0 + j];
    }
    __syncthreads();
    for (int k = 0; k < 32; ++k) {
      if (t == 0) {
        double dk = sqrt(fmax(D[k][k], 1e-300));
        dsh[k] = dk;
        dinv[k] = 1.0 / (dk * dk);
      }
      __syncthreads();
      double inv = dinv[k];
      for (int e = t; e < 1024; e += 256) {
        int i = e >> 5, j = e & 31;
        if (i > k && j > k && j <= i) D[i][j] -= D[i][k] * D[j][k] * inv;
      }
      __syncthreads();
    }
    for (int e = t; e < 1024; e += 256) {
      int i = e >> 5, j = e & 31;
      if (i > j) D[i][j] /= dsh[j];
      else if (i == j) D[i][j] = dsh[i];
    }
    __syncthreads();
    if (t < 32) {
      double lg = log(dsh[t]);
#pragma unroll
      for (int off = 16; off > 0; off >>= 1) lg += __shfl_down(lg, off, 64);
      if (t == 0) lsum += 2.0 * lg;
    }
    int r = d0 + 32 + t;
    bool act = (r < Dn);
    double x[32];
    if (act) {
#pragma unroll
      for (int j = 0; j < 32; ++j) x[j] = A[(ll)r * Dn + d0 + j];
#pragma unroll
      for (int j = 0; j < 32; ++j) {
        double s = x[j];
#pragma unroll
        for (int i = 0; i < j; ++i) s -= x[i] * D[j][i];
        x[j] = s / D[j][j];
      }
#pragma unroll
      for (int j = 0; j < 32; ++j) A[(ll)r * Dn + d0 + j] = x[j];
    }
    __syncthreads();
    int ntrail = Dn - d0 - 32;
    for (int cc = 0; cc < ntrail; cc += 32) {
      for (int e = t; e < 1024; e += 256) {
        int i = e >> 5, j = e & 31;
        if (cc + i < ntrail) Lc[i][j] = A[(ll)(d0 + 32 + cc + i) * Dn + d0 + j];
      }
      __syncthreads();
      if (act) {
        int cend = min(cc + 32, r - d0 - 32 + 1);
        for (int ci = cc; ci < cend; ++ci) {
          double s = 0.0;
#pragma unroll
          for (int k2 = 0; k2 < 32; ++k2) s += x[k2] * Lc[ci - cc][k2];
          A[(ll)r * Dn + d0 + 32 + ci] -= s;
        }
      }
      __syncthreads();
    }
  }
  if (t == 0) ld[blockIdx.x] = lsum;
}

__global__ void cov_final(const double* __restrict__ ld, float* __restrict__ outp) {
  outp[0] = (float)(-0.1 / (3.0 * 256.0) * (ld[0] + ld[1] + ld[2]));
}

// ---------------- output head: xph[M][256] @ outT[96][256]^T, scatter+denorm --
__global__ __launch_bounds__(256) void out_mfma(
    const ushort_t* __restrict__ A, const ushort_t* __restrict__ B,
    const float* __restrict__ bias, const float* __restrict__ stdev,
    const float* __restrict__ mean, float* __restrict__ out) {
  constexpr int M = Bn * Cn, N = Pn, K = Dn;
  __shared__ ushort_t As[128][40];
  __shared__ ushort_t Bs[128][40];
  int t = threadIdx.x;
  int m0 = blockIdx.y * 128;
  int w = t >> 6, lane = t & 63;
  int wm = (w >> 1) * 64, wn = (w & 1) * 64;
  int lrow = lane & 15, kq = lane >> 4;
  int r0 = t >> 2, kc = (t & 3) * 8;
  f32x4 acc[4][4] = {};
  for (int k0 = 0; k0 < K; k0 += 32) {
    bf16x8 z8 = {};
#pragma unroll
    for (int e = 0; e < 2; ++e) {
      int row = e * 64 + r0;
      bf16x8 va = *reinterpret_cast<const bf16x8*>(&A[(ll)(m0 + row) * K + k0 + kc]);
      bf16x8 vb = z8;
      if (row < N) vb = *reinterpret_cast<const bf16x8*>(&B[(ll)row * K + k0 + kc]);
      *reinterpret_cast<bf16x8*>(&As[row][kc]) = va;
      *reinterpret_cast<bf16x8*>(&Bs[row][kc]) = vb;
    }
    __syncthreads();
    bf16x8 af[4], bfr[4];
#pragma unroll
    for (int i = 0; i < 4; ++i)
      af[i] = *reinterpret_cast<const bf16x8*>(&As[wm + i * 16 + lrow][kq * 8]);
#pragma unroll
    for (int j = 0; j < 4; ++j)
      bfr[j] = *reinterpret_cast<const bf16x8*>(&Bs[wn + j * 16 + lrow][kq * 8]);
#pragma unroll
    for (int i = 0; i < 4; ++i)
#pragma unroll
      for (int j = 0; j < 4; ++j)
        acc[i][j] = __builtin_amdgcn_mfma_f32_16x16x32_bf16(af[i], bfr[j],
                                                            acc[i][j], 0, 0, 0);
    __syncthreads();
  }
#pragma unroll
  for (int i = 0; i < 4; ++i) {
    int mb = m0 + wm + i * 16 + kq * 4;
#pragma unroll
    for (int j = 0; j < 4; ++j) {
      int p = wn + j * 16 + lrow;
      if (p >= N) continue;
      float bv = bias[p];
#pragma unroll
      for (int reg = 0; reg < 4; ++reg) {
        int m = mb + reg;
        int b = m >> 11, c = m & 2047;
        float v = acc[i][j][reg] + bv;
        out[((ll)(b * Pn + p)) * Cn + c] = v * stdev[m] + mean[m];
      }
    }
  }
}

// =====================================================================
extern "C" void kernel_launch(void* const* d_in, const int* in_sizes, int n_in,
                              void* d_out, int out_size, void* d_ws, size_t ws_size,
                              hipStream_t stream) {
  (void)in_sizes; (void)n_in; (void)out_size; (void)ws_size;
  const float* x_enc = (const float*)d_in[0];
  const float* in_w = (const float*)d_in[4];
  const float* in_b = (const float*)d_in[5];
  const float* lq[3] = {(const float*)d_in[6], (const float*)d_in[7],
                        (const float*)d_in[8]};
  const float* down_w = (const float*)d_in[9];
  const float* down_b = (const float*)d_in[10];
  const float* down_ln = (const float*)d_in[11];
  const float* pred_w = (const float*)d_in[12];
  const float* pred_b = (const float*)d_in[13];
  const float* up_w = (const float*)d_in[14];
  const float* up_b = (const float*)d_in[15];
  const float* up_ln = (const float*)d_in[16];
  const float* out_w = (const float*)d_in[17];
  const float* out_b = (const float*)d_in[18];
  float* out = (float*)d_out;

  float* ws = (float*)d_ws;
  size_t off = 0;
  auto alloc = [&](size_t n) {
    n = (n + 3) & ~(size_t)3;  // 16B alignment
    float* p = ws + off;
    off += n;
    return p;
  };
  float* mean = alloc((size_t)Bn * Cn);
  float* stdevv = alloc((size_t)Bn * Cn);
  float* cmean = alloc(256);
  float* cistd = alloc(256);
  double* part = (double*)alloc(64 * 512 * 2);
  double* ld = (double*)alloc(16);
  double* covd = (double*)alloc(3 * 65536 * 2);
  float* s1 = alloc((size_t)Bn * 512 * Dn);
  float* s2 = alloc((size_t)Bn * 128 * Dn);
  float* s3 = alloc((size_t)Bn * 32 * Dn);
  float* attn = alloc((size_t)Bn * 512 * 2048);     // f32 scores; also xnT(bf16), xc
  float* sbuf = alloc((size_t)16777216);            // attn_bf / o2 f32 / covpart
  ushort_t* h_bf = (ushort_t*)alloc((size_t)Bn * Cn * Dn / 2);
  ushort_t* s1b = (ushort_t*)alloc((size_t)Bn * 512 * Dn / 2);
  ushort_t* s2b = (ushort_t*)alloc((size_t)Bn * 128 * Dn / 2);
  ushort_t* s3b = (ushort_t*)alloc((size_t)Bn * 32 * Dn / 2);
  ushort_t* xpb = (ushort_t*)alloc((size_t)Bn * 32 * Dn / 2);
  ushort_t* xu0b = (ushort_t*)alloc((size_t)Bn * 128 * Dn / 2);
  ushort_t* xu1b = (ushort_t*)alloc((size_t)Bn * 512 * Dn / 2);
  ushort_t* qd_b = (ushort_t*)alloc(512 * 256 / 2);
  ushort_t* lqb0 = (ushort_t*)alloc(512 * 256 / 2);
  ushort_t* lqb1 = (ushort_t*)alloc(128 * 256 / 2);
  ushort_t* lqb2 = (ushort_t*)alloc(32 * 256 / 2);
  ushort_t* in_wT = (ushort_t*)alloc(256 * 720 / 2);
  ushort_t* downT = (ushort_t*)alloc(12 * 65536 / 2);
  ushort_t* upT = (ushort_t*)alloc(12 * 65536 / 2);
  ushort_t* predT = (ushort_t*)alloc(65536 / 2);
  ushort_t* outT = (ushort_t*)alloc(96 * 256 / 2);
  ushort_t* q_bf = (ushort_t*)alloc((size_t)Bn * 2048 * Dn / 2);  // also o1, xph
  ushort_t* k_bf = (ushort_t*)alloc((size_t)Bn * 2048 * Dn / 2);
  ushort_t* vT = (ushort_t*)alloc((size_t)Bn * 2048 * Dn / 2);

  ushort_t* xnT = (ushort_t*)attn;
  ushort_t* attn_b = (ushort_t*)sbuf;
  float* o2 = sbuf;
  double* covpart = (double*)sbuf;
  const float scale = 0.0625f;
  const float* npf = nullptr;

  // ---- prep: stats, normalize+transpose input, weight converts ----
  instnorm_stats<<<dim3(Cn / 256, Bn), 256, 0, stream>>>(x_enc, mean, stdevv);
  normT_kernel<<<dim3(Cn / 32, CDIV(Sn, 32), Bn), 256, 0, stream>>>(x_enc, xnT, mean,
                                                                    stdevv);
  cvtT_kernel<<<dim3(8, 8, 12), 256, 0, stream>>>(down_w, downT, 256, 256);
  cvtT_kernel<<<dim3(8, 8, 12), 256, 0, stream>>>(up_w, upT, 256, 256);
  cvtT_kernel<<<dim3(8, 8, 1), 256, 0, stream>>>(pred_w, predT, 256, 256);
  cvtT_kernel<<<dim3(8, CDIV(Sn, 32), 1), 256, 0, stream>>>(in_w, in_wT, Sn, 256);
  cvtT_kernel<<<dim3(3, 8, 1), 256, 0, stream>>>(out_w, outT, 256, Pn);
  cvt_bf<<<512, 256, 0, stream>>>(lq[0], lqb0, 512 * 256);
  cvt_bf<<<128, 256, 0, stream>>>(lq[1], lqb1, 128 * 256);
  cvt_bf<<<32, 256, 0, stream>>>(lq[2], lqb2, 32 * 256);

  // ---- h = xn^T @ in_w + b : bf16 out ----
  gemm_bf<2><<<dim3(2, 16, Bn), 256, 0, stream>>>(
      xnT, in_wT, Cn, Dn, Sn, Sn, Sn, (ll)Cn * Sn, 0, in_b, 1.f,
      nullptr, 0, 0, h_bf, Dn, (ll)Cn * Dn);

  ushort_t* lqb[3] = {lqb0, lqb1, lqb2};
  float* skf[3] = {s1, s2, s3};
  ushort_t* skb[3] = {s1b, s2b, s3b};
  int Ls[4] = {2048, 512, 128, 32};
  const ushort_t* xinb = h_bf;

  // ---------------- down layers ----------------
  for (int i = 0; i < 3; ++i) {
    int L = Ls[i], Lq = Ls[i + 1];
    const ushort_t* WqT = downT + (size_t)(i * 4 + 0) * 65536;
    const ushort_t* WkT = downT + (size_t)(i * 4 + 1) * 65536;
    const ushort_t* WvT = downT + (size_t)(i * 4 + 2) * 65536;
    const ushort_t* WoT = downT + (size_t)(i * 4 + 3) * 65536;
    const float* bq = down_b + (i * 4 + 0) * 256;
    const float* bk = down_b + (i * 4 + 1) * 256;
    const float* bv = down_b + (i * 4 + 2) * 256;
    const float* bo = down_b + (i * 4 + 3) * 256;

    gemm_bf<2><<<dim3(2, CDIV(Lq, 128), 1), 256, 0, stream>>>(
        lqb[i], WqT, Lq, Dn, Dn, Dn, Dn, 0, 0, bq, 1.f, nullptr, 0, 0, qd_b, Dn, 0);
    gemm_bf<2><<<dim3(2, (Bn * L) / 128, 1), 256, 0, stream>>>(
        xinb, WkT, Bn * L, Dn, Dn, Dn, Dn, 0, 0, bk, 1.f, nullptr, 0, 0, k_bf, Dn, 0);
    gemm_bf<4><<<dim3(2, L / 128, Bn), 256, 0, stream>>>(
        xinb, WvT, L, Dn, Dn, Dn, Dn, (ll)L * Dn, 0, bv, 1.f, nullptr, 0, 0,
        vT, L, (ll)Dn * L);
    gemm_bf<1><<<dim3(L / 128, CDIV(Lq, 128), Bn), 256, 0, stream>>>(
        qd_b, k_bf, Lq, L, Dn, Dn, Dn, 0, (ll)L * Dn, npf, scale,
        attn, L, (ll)Lq * L, nullptr, 0, 0);
    if (L == 2048) softmax_bf<2048><<<Bn * Lq, 256, 0, stream>>>(attn, attn_b);
    else if (L == 512) softmax_bf<512><<<Bn * Lq, 256, 0, stream>>>(attn, attn_b);
    else softmax_bf<128><<<Bn * Lq, 256, 0, stream>>>(attn, attn_b);
    gemm_bf<2><<<dim3(2, CDIV(Lq, 128), Bn), 256, 0, stream>>>(
        attn_b, vT, Lq, Dn, L, L, L, (ll)Lq * L, (ll)Dn * L, npf, 1.f,
        nullptr, 0, 0, q_bf, Dn, (ll)Lq * Dn);
    gemm_bf<1><<<dim3(2, CDIV(Bn * Lq, 128), 1), 256, 0, stream>>>(
        q_bf, WoT, Bn * Lq, Dn, Dn, Dn, Dn, 0, 0, bo, 1.f, o2, Dn, 0, nullptr, 0, 0);
    ln_kernel<<<Bn * Lq, 256, 0, stream>>>(o2, nullptr, skf[i], skb[i], 0,
                                           down_ln + (i * 2 + 0) * 256,
                                           down_ln + (i * 2 + 1) * 256);
    xinb = skb[i];
  }

  // ---------------- covariance loss (split-K f64 Gram + f64 Cholesky) --------
  int nrs[3] = {Bn * 512, Bn * 128, Bn * 32};
  float* xc = attn;
  for (int j = 0; j < 3; ++j) {
    int nr = nrs[j];
    colstat_partial<<<64, 256, 0, stream>>>(skf[j], part, nr);
    colstat_final<<<1, 256, 0, stream>>>(part, cmean, cistd, nr);
    xcnorm_kernel<<<1024, 256, 0, stream>>>(skf[j], xc, cmean, cistd, (ll)nr * Dn);
    cov_gemm_f64_split<<<dim3(8, 8, 16), 256, 0, stream>>>(xc, covpart, nr);
    cov_reduce<<<256, 256, 0, stream>>>(covpart, covd + (size_t)j * 65536,
                                        1.0 / (double)(nr - 1));
  }
  cholesky_logdet_f64<<<3, 256, 0, stream>>>(covd, ld);
  cov_final<<<1, 1, 0, stream>>>(ld, out + 6291456);

  // ---------------- pred head ----------------
  gemm_bf<2><<<dim3(2, 8, 1), 256, 0, stream>>>(
      s3b, predT, Bn * 32, Dn, Dn, Dn, Dn, 0, 0, pred_b, 1.f,
      nullptr, 0, 0, xpb, Dn, 0);

  // ---------------- up layers ----------------
  int Lks[3] = {32, 128, 512}, Lqs[3] = {128, 512, 2048};
  const ushort_t* qinb[3] = {s2b, s1b, h_bf};
  const ushort_t* xinbs[3] = {xpb, xu0b, xu1b};
  ushort_t* xoutb[3] = {xu0b, xu1b, q_bf};  // final writes xph into q_bf
  for (int i = 0; i < 3; ++i) {
    int Lk = Lks[i], Lq = Lqs[i];
    const ushort_t* WqT = upT + (size_t)(i * 4 + 0) * 65536;
    const ushort_t* WkT = upT + (size_t)(i * 4 + 1) * 65536;
    const ushort_t* WvT = upT + (size_t)(i * 4 + 2) * 65536;
    const ushort_t* WoT = upT + (size_t)(i * 4 + 3) * 65536;
    const float* bq = up_b + (i * 4 + 0) * 256;
    const float* bk = up_b + (i * 4 + 1) * 256;
    const float* bv = up_b + (i * 4 + 2) * 256;
    const float* bo = up_b + (i * 4 + 3) * 256;

    gemm_bf<2><<<dim3(2, (Bn * Lq) / 128, 1), 256, 0, stream>>>(
        qinb[i], WqT, Bn * Lq, Dn, Dn, Dn, Dn, 0, 0, bq, 1.f,
        nullptr, 0, 0, q_bf, Dn, 0);
    gemm_bf<2><<<dim3(2, CDIV(Bn * Lk, 128), 1), 256, 0, stream>>>(
        xinbs[i], WkT, Bn * Lk, Dn, Dn, Dn, Dn, 0, 0, bk, 1.f,
        nullptr, 0, 0, k_bf, Dn, 0);
    gemm_bf<4><<<dim3(2, CDIV(Lk, 128), Bn), 256, 0, stream>>>(
        xinbs[i], WvT, Lk, Dn, Dn, Dn, Dn, (ll)Lk * Dn, 0, bv, 1.f,
        nullptr, 0, 0, vT, Lk, (ll)Dn * Lk);
    gemm_bf<1><<<dim3(CDIV(Lk, 128), CDIV(Lq, 128), Bn), 256, 0, stream>>>(
        q_bf, k_bf, Lq, Lk, Dn, Dn, Dn, (ll)Lq * Dn, (ll)Lk * Dn, npf, scale,
        attn, Lk, (ll)Lq * Lk, nullptr, 0, 0);
    if (Lk == 32) softmax_bf<32><<<Bn * Lq, 256, 0, stream>>>(attn, attn_b);
    else if (Lk == 128) softmax_bf<128><<<Bn * Lq, 256, 0, stream>>>(attn, attn_b);
    else softmax_bf<512><<<Bn * Lq, 256, 0, stream>>>(attn, attn_b);
    gemm_bf<2><<<dim3(2, CDIV(Lq, 128), Bn), 256, 0, stream>>>(
        attn_b, vT, Lq, Dn, Lk, Lk, Lk, (ll)Lq * Lk, (ll)Dn * Lk, npf, 1.f,
        nullptr, 0, 0, q_bf, Dn, (ll)Lq * Dn);
    gemm_bf<1><<<dim3(2, (Bn * Lq) / 128, 1), 256, 0, stream>>>(
        q_bf, WoT, Bn * Lq, Dn, Dn, Dn, Dn, 0, 0, bo, 1.f, o2, Dn, 0, nullptr, 0, 0);
    ln_kernel<<<Bn * Lq, 256, 0, stream>>>(o2, qinb[i], nullptr, xoutb[i],
                                           (i == 2) ? 1 : 0,
                                           up_ln + (i * 2 + 0) * 256,
                                           up_ln + (i * 2 + 1) * 256);
  }

  // ---------------- output head: MFMA + transpose + de-norm ----------------
  out_mfma<<<dim3(1, (Bn * Cn) / 128, 1), 256, 0, stream>>>(q_bf, outT, out_b,
                                                            stdevv, mean, out);
}

// Round 6
// 2044.060 us; speedup vs baseline: 4.0984x; 1.2182x over previous
//
#include <hip/hip_runtime.h>
#include <hip/hip_bf16.h>
#include <math.h>

#define CDIV(a, b) (((a) + (b) - 1) / (b))
typedef long long ll;
typedef unsigned short ushort_t;

constexpr int Bn = 32;    // batch
constexpr int Sn = 720;   // seq len
constexpr int SnP = 736;  // seq len padded to K-step multiple
constexpr int Cn = 2048;  // channels (tokens after transpose)
constexpr int Dn = 256;   // d_model
constexpr int Pn = 96;    // pred len

typedef __attribute__((ext_vector_type(8))) short bf16x8;
typedef __attribute__((ext_vector_type(4))) float f32x4;

__device__ inline ushort_t rne1(float x) {
  unsigned u = __float_as_uint(x);
  u = (u + 0x7fffu + ((u >> 16) & 1u)) >> 16;
  return (ushort_t)u;
}
__device__ inline float b2f(ushort_t u) { return __uint_as_float(((unsigned)u) << 16); }

__device__ inline void gl_lds16(const void* g, void* l) {
  __builtin_amdgcn_global_load_lds(
      (const __attribute__((address_space(1))) void*)g,
      (__attribute__((address_space(3))) void*)l, 16, 0, 0);
}

// ---------------- instance norm stats over time axis ----------------
__global__ void instnorm_stats(const float* __restrict__ x,
                               float* __restrict__ mean, float* __restrict__ stdev) {
  int c = blockIdx.x * 256 + threadIdx.x;
  int b = blockIdx.y;
  const float* p = x + (ll)b * Sn * Cn + c;
  float s = 0.f, q = 0.f;
  for (int t = 0; t < Sn; ++t) {
    float v = p[(ll)t * Cn];
    s += v; q += v * v;
  }
  float m = s / (float)Sn;
  float var = q / (float)Sn - m * m;
  var = fmaxf(var, 0.f);
  mean[b * Cn + c] = m;
  stdev[b * Cn + c] = sqrtf(var + 1e-5f);
}

// ---------------- normalize + transpose: x[b][s][c] -> xnT[b][c][s] bf16 (K-pad)
__global__ void normT_kernel(const float* __restrict__ X, ushort_t* __restrict__ D,
                             const float* __restrict__ mean,
                             const float* __restrict__ stdev) {
  int b = blockIdx.z;
  __shared__ float tl[32][33];
  int t = threadIdx.x;
  int tx = t & 31, ty = t >> 5;
  int s0 = blockIdx.y * 32, c0 = blockIdx.x * 32;
#pragma unroll
  for (int e = 0; e < 4; ++e) {
    int s = s0 + ty + 8 * e;
    tl[ty + 8 * e][tx] = (s < Sn) ? X[((ll)b * Sn + s) * Cn + c0 + tx] : 0.f;
  }
  __syncthreads();
#pragma unroll
  for (int e = 0; e < 4; ++e) {
    int c = c0 + ty + 8 * e, s = s0 + tx;
    if (s < SnP) {
      float mu = mean[b * Cn + c], sd = stdev[b * Cn + c];
      float v = (s < Sn) ? (tl[tx][ty + 8 * e] - mu) / sd : 0.f;
      D[((ll)b * Cn + c) * SnP + s] = rne1(v);
    }
  }
}

// ---------------- transpose-convert: W[K][N] f32 -> WT[N][KP] bf16 ------------
__global__ void cvtT_kernel(const float* __restrict__ S, ushort_t* __restrict__ D,
                            int K, int N, int KP) {
  int z = blockIdx.z;
  S += (ll)z * K * N;
  D += (ll)z * N * KP;
  __shared__ float tl[32][33];
  int t = threadIdx.x;
  int tx = t & 31, ty = t >> 5;
  int k0 = blockIdx.y * 32, n0 = blockIdx.x * 32;
#pragma unroll
  for (int e = 0; e < 4; ++e) {
    int k = k0 + ty + 8 * e;
    tl[ty + 8 * e][tx] = (k < K && n0 + tx < N) ? S[(ll)k * N + n0 + tx] : 0.f;
  }
  __syncthreads();
#pragma unroll
  for (int e = 0; e < 4; ++e) {
    int n = n0 + ty + 8 * e, kk = k0 + tx;
    if (n < N && kk < KP) D[(ll)n * KP + kk] = rne1(tl[tx][ty + 8 * e]);
  }
}

__global__ void cvt_bf(const float* __restrict__ S, ushort_t* __restrict__ D, int n) {
  int i = blockIdx.x * 256 + threadIdx.x;
  if (i < n) D[i] = rne1(S[i]);
}

// ---------------- canonical bf16 MFMA GEMM: C = A[M][K] * B[N][K]^T ----------
// global_load_lds staging; K must be a multiple of 32; OOB rows clamped.
// MODE bits: 1 = write f32 C (ldcf), 2 = write bf16 C (ldcb), 4 = write bf16 C^T
template <int MODE>
__global__ __launch_bounds__(256) void gemm_bf(
    const ushort_t* __restrict__ A, const ushort_t* __restrict__ B,
    int M, int N, int K, int lda, int ldb, ll sA, ll sB,
    const float* __restrict__ bias, float alpha,
    float* __restrict__ Cf, int ldcf, ll sCf,
    ushort_t* __restrict__ Cb, int ldcb, ll sCb) {
  int g = blockIdx.z;
  A += (ll)g * sA;
  B += (ll)g * sB;
  if (MODE & 1) Cf += (ll)g * sCf;
  if (MODE & 6) Cb += (ll)g * sCb;
  __shared__ ushort_t lds_ab[2][128][32];
  int t = threadIdx.x;
  int m0 = blockIdx.y * 128, n0 = blockIdx.x * 128;
  int w = t >> 6, lane = t & 63;
  int wm = (w >> 1) * 64, wn = (w & 1) * 64;
  int lrow = lane & 15, kq = lane >> 4;
  int srow = lane >> 2, skcol = (lane & 3) * 8;
  f32x4 acc[4][4] = {};
  for (int k0 = 0; k0 < K; k0 += 32) {
#pragma unroll
    for (int cc = 0; cc < 4; ++cc) {
      int c = w * 4 + cc;
      int tile = c >> 3, rb = (c & 7) * 16;
      int row = rb + srow;
      const ushort_t* src;
      if (tile == 0) {
        int gm = min(m0 + row, M - 1);
        src = &A[(ll)gm * lda + k0 + skcol];
      } else {
        int gn = min(n0 + row, N - 1);
        src = &B[(ll)gn * ldb + k0 + skcol];
      }
      gl_lds16(src, &lds_ab[tile][rb][0]);
    }
    __syncthreads();
    bf16x8 af[4], bfr[4];
#pragma unroll
    for (int i = 0; i < 4; ++i)
      af[i] = *reinterpret_cast<const bf16x8*>(&lds_ab[0][wm + i * 16 + lrow][kq * 8]);
#pragma unroll
    for (int j = 0; j < 4; ++j)
      bfr[j] = *reinterpret_cast<const bf16x8*>(&lds_ab[1][wn + j * 16 + lrow][kq * 8]);
#pragma unroll
    for (int i = 0; i < 4; ++i)
#pragma unroll
      for (int j = 0; j < 4; ++j)
        acc[i][j] = __builtin_amdgcn_mfma_f32_16x16x32_bf16(af[i], bfr[j],
                                                            acc[i][j], 0, 0, 0);
    __syncthreads();
  }
#pragma unroll
  for (int i = 0; i < 4; ++i) {
    int mb = m0 + wm + i * 16 + kq * 4;
    if (mb >= M) continue;
#pragma unroll
    for (int j = 0; j < 4; ++j) {
      int c = n0 + wn + j * 16 + lrow;
      if (c >= N) continue;
      float bv = bias ? bias[c] : 0.f;
#pragma unroll
      for (int reg = 0; reg < 4; ++reg) {
        int m = mb + reg;
        float v = acc[i][j][reg] * alpha + bv;
        if (MODE & 1) Cf[(ll)m * ldcf + c] = v;
        if (MODE & 2) Cb[(ll)m * ldcb + c] = rne1(v);
        if (MODE & 4) Cb[(ll)c * ldcb + m] = rne1(v);
      }
    }
  }
}

// ---------------- block reduction helper (blockDim = 256) ----------------
__device__ inline float blk_reduce(float v, volatile float* sh, int op) {
  int lane = threadIdx.x & 63, w = threadIdx.x >> 6;
#pragma unroll
  for (int off = 32; off > 0; off >>= 1) {
    float o = __shfl_down(v, off, 64);
    v = op ? fmaxf(v, o) : (v + o);
  }
  __syncthreads();
  if (lane == 0) sh[w] = v;
  __syncthreads();
  float r = op ? fmaxf(fmaxf(sh[0], sh[1]), fmaxf(sh[2], sh[3]))
               : (sh[0] + sh[1] + sh[2] + sh[3]);
  return r;
}

// ---------------- row softmax: f32 scores in, bf16 probs out ----------------
template <int LL>
__global__ void softmax_bf(const float* __restrict__ S, ushort_t* __restrict__ P) {
  constexpr int NE = (LL + 255) / 256;
  __shared__ float sh[4];
  ll row = blockIdx.x;
  const float* p = S + row * (ll)LL;
  ushort_t* q = P + row * (ll)LL;
  int t = threadIdx.x;
  float e[NE];
  float mx = -INFINITY;
#pragma unroll
  for (int k = 0; k < NE; ++k) {
    int i = t + k * 256;
    if (i < LL) { e[k] = p[i]; mx = fmaxf(mx, e[k]); }
  }
  mx = blk_reduce(mx, sh, 1);
  float sum = 0.f;
#pragma unroll
  for (int k = 0; k < NE; ++k) {
    int i = t + k * 256;
    if (i < LL) { e[k] = __expf(e[k] - mx); sum += e[k]; }
  }
  sum = blk_reduce(sum, sh, 0);
  float inv = 1.f / sum;
#pragma unroll
  for (int k = 0; k < NE; ++k) {
    int i = t + k * 256;
    if (i < LL) q[i] = rne1(e[k] * inv);
  }
}

// ---------------- LayerNorm over D=256; optional bf16 residual ----------------
__global__ void ln_kernel(const float* __restrict__ X, const ushort_t* __restrict__ RESb,
                          float* __restrict__ Yf, ushort_t* __restrict__ Yb, int postadd,
                          const float* __restrict__ gamma, const float* __restrict__ beta) {
  __shared__ float sh[4];
  ll row = blockIdx.x;
  int t = threadIdx.x;
  float r = RESb ? b2f(RESb[row * Dn + t]) : 0.f;
  float v = X[row * Dn + t] + r;
  float m = blk_reduce(v, sh, 0) * (1.f / (float)Dn);
  float d = v - m;
  float var = blk_reduce(d * d, sh, 0) * (1.f / (float)Dn);
  float y = d * rsqrtf(var + 1e-5f) * gamma[t] + beta[t];
  if (Yf) Yf[row * Dn + t] = y;
  if (Yb) Yb[row * Dn + t] = rne1(y + (postadd ? r : 0.f));
}

// ---------------- covariance column stats (f64 partials) ----------------
__global__ void colstat_partial(const float* __restrict__ X, double* __restrict__ part,
                                int nrows) {
  int blk = blockIdx.x, t = threadIdx.x;
  int chunk = CDIV(nrows, 64);
  int r0 = blk * chunk, r1 = min(nrows, r0 + chunk);
  double s = 0.0, q = 0.0;
  for (int r = r0; r < r1; ++r) {
    double v = (double)X[(ll)r * Dn + t];
    s += v; q += v * v;
  }
  part[blk * 512 + t] = s;
  part[blk * 512 + 256 + t] = q;
}

__global__ void colstat_final(const double* __restrict__ part, float* __restrict__ cmean,
                              float* __restrict__ cistd, int nrows) {
  int t = threadIdx.x;
  double s = 0.0, q = 0.0;
  for (int b = 0; b < 64; ++b) {
    s += part[b * 512 + t];
    q += part[b * 512 + 256 + t];
  }
  double m = s / (double)nrows;
  double var = (q - (double)nrows * m * m) / (double)(nrows - 1);
  var = fmax(var, 0.0);
  cmean[t] = (float)m;
  cistd[t] = (float)(1.0 / (sqrt(var) + 1e-5));
}

__global__ void xcnorm_kernel(const float* __restrict__ X, float* __restrict__ XC,
                              const float* __restrict__ cmean,
                              const float* __restrict__ cistd, ll n) {
  for (ll i = blockIdx.x * 256LL + threadIdx.x; i < n; i += (ll)gridDim.x * 256) {
    int d = (int)(i & 255);
    XC[i] = (X[i] - cmean[d]) * cistd[d];
  }
}

// ---------------- split-K cov Gram, f64 partials ----------------
__global__ __launch_bounds__(256) void cov_gemm_f64_split(const float* __restrict__ XC,
                                                          double* __restrict__ part,
                                                          int nr) {
  __shared__ float Am[32][33];
  __shared__ float Bq[32][33];
  int t = threadIdx.x;
  int tx = t & 31, ty = t >> 5;
  int m0 = blockIdx.y * 32, n0 = blockIdx.x * 32;
  int z = blockIdx.z;
  int chunk = nr >> 4;
  int kbeg = z * chunk, kend = kbeg + chunk;
  double acc[4] = {0.0, 0.0, 0.0, 0.0};
  for (int k0 = kbeg; k0 < kend; k0 += 32) {
#pragma unroll
    for (int e = 0; e < 4; ++e) {
      int idx = t + e * 256;
      int kk = idx >> 5, mm = idx & 31;
      Am[kk][mm] = XC[(ll)(k0 + kk) * Dn + m0 + mm];
      Bq[kk][mm] = XC[(ll)(k0 + kk) * Dn + n0 + mm];
    }
    __syncthreads();
#pragma unroll 8
    for (int kk = 0; kk < 32; ++kk) {
      float bv = Bq[kk][tx];
#pragma unroll
      for (int r = 0; r < 4; ++r)
        acc[r] += (double)Am[kk][ty + 8 * r] * (double)bv;
    }
    __syncthreads();
  }
#pragma unroll
  for (int r = 0; r < 4; ++r) {
    int m = m0 + ty + 8 * r, n = n0 + tx;
    part[(ll)z * 65536 + m * 256 + n] = acc[r];
  }
}

__global__ void cov_reduce(const double* __restrict__ part, double* __restrict__ Cd,
                           double inv) {
  int idx = blockIdx.x * 256 + threadIdx.x;
  double s = 0.0;
#pragma unroll
  for (int z = 0; z < 16; ++z) s += part[(ll)z * 65536 + idx];
  int m = idx >> 8, n = idx & 255;
  Cd[idx] = s * inv + ((m == n) ? 1e-5 : 0.0);
}

// ---------------- register-panel left-looking f64 Cholesky + logdet ----------
// 1024 threads; thread t owns row r = d0 + (t>>2), cols c0..c0+7 (c0=(t&3)*8)
// of the current 32-wide panel, in registers. 1 barrier per factor step.
__global__ __launch_bounds__(1024) void cholesky_logdet_f64(double* __restrict__ mats,
                                                            double* __restrict__ ld) {
  double* A = mats + (ll)blockIdx.x * 65536;
  int t = threadIdx.x;
  __shared__ double Ltop[32][33];
  __shared__ double colk[2][256];
  double lsum = 0.0;
  int rrel = t >> 2;
  int cg = t & 3;
  int c0 = cg * 8;
  for (int kb = 0; kb < 8; ++kb) {
    int d0 = kb * 32;
    int r = d0 + rrel;
    bool act = (r < 256);
    double x[8];
    if (act) {
#pragma unroll
      for (int j = 0; j < 8; ++j) x[j] = A[(ll)r * 256 + d0 + c0 + j];
    }
    // history: x -= L[r][0:d0] . L[d0+c][0:d0]
    for (int hb = 0; hb < kb; ++hb) {
      int k0 = hb * 32;
      { int c = t >> 5, kk = t & 31;
        Ltop[c][kk] = A[(ll)(d0 + c) * 256 + k0 + kk]; }
      __syncthreads();
      if (act) {
#pragma unroll
        for (int s4 = 0; s4 < 4; ++s4) {
          double av[8];
#pragma unroll
          for (int q = 0; q < 8; ++q) av[q] = A[(ll)r * 256 + k0 + s4 * 8 + q];
#pragma unroll
          for (int j = 0; j < 8; ++j) {
            double s = 0.0;
#pragma unroll
            for (int q = 0; q < 8; ++q) s += av[q] * Ltop[c0 + j][s4 * 8 + q];
            x[j] -= s;
          }
        }
      }
      __syncthreads();
    }
    // factor: unscaled outer-product recurrence, 1 barrier/step
    double dloc[8];
#pragma unroll
    for (int k8 = 0; k8 < 4; ++k8) {
#pragma unroll
      for (int k2 = 0; k2 < 8; ++k2) {
        int k = k8 * 8 + k2;
        int buf = k & 1;
        if (act && cg == k8) colk[buf][rrel] = x[k2];
        __syncthreads();
        double piv = fmax(colk[buf][k], 1e-300);
        if (t == 0) lsum += log(piv);  // logdet = sum log(d_k^2) = sum log(piv)
        if (cg == k8) dloc[k2] = sqrt(piv);
        double inv = 1.0 / piv;
        if (act && rrel > k) {
          double xr = colk[buf][rrel];
#pragma unroll
          for (int j = 0; j < 8; ++j) {
            if (c0 + j > k) x[j] -= xr * colk[buf][c0 + j] * inv;
          }
        }
      }
    }
    // scale + write back panel
    if (act) {
#pragma unroll
      for (int j = 0; j < 8; ++j) A[(ll)r * 256 + d0 + c0 + j] = x[j] / dloc[j];
    }
    __syncthreads();
  }
  if (t == 0) ld[blockIdx.x] = lsum;
}

__global__ void cov_final(const double* __restrict__ ld, float* __restrict__ outp) {
  outp[0] = (float)(-0.1 / (3.0 * 256.0) * (ld[0] + ld[1] + ld[2]));
}

// ---------------- output head: xph[M][256] @ outT[96][256]^T, scatter+denorm --
__global__ __launch_bounds__(256) void out_mfma(
    const ushort_t* __restrict__ A, const ushort_t* __restrict__ B,
    const float* __restrict__ bias, const float* __restrict__ stdev,
    const float* __restrict__ mean, float* __restrict__ out) {
  constexpr int M = Bn * Cn, N = Pn, K = Dn;
  __shared__ ushort_t lds_ab[2][128][32];
  int t = threadIdx.x;
  int m0 = blockIdx.y * 128;
  int w = t >> 6, lane = t & 63;
  int wm = (w >> 1) * 64, wn = (w & 1) * 64;
  int lrow = lane & 15, kq = lane >> 4;
  int srow = lane >> 2, skcol = (lane & 3) * 8;
  f32x4 acc[4][4] = {};
  for (int k0 = 0; k0 < K; k0 += 32) {
#pragma unroll
    for (int cc = 0; cc < 4; ++cc) {
      int c = w * 4 + cc;
      int tile = c >> 3, rb = (c & 7) * 16;
      int row = rb + srow;
      const ushort_t* src;
      if (tile == 0) {
        src = &A[(ll)(m0 + row) * K + k0 + skcol];
      } else {
        int gn = min(row, N - 1);
        src = &B[(ll)gn * K + k0 + skcol];
      }
      gl_lds16(src, &lds_ab[tile][rb][0]);
    }
    __syncthreads();
    bf16x8 af[4], bfr[4];
#pragma unroll
    for (int i = 0; i < 4; ++i)
      af[i] = *reinterpret_cast<const bf16x8*>(&lds_ab[0][wm + i * 16 + lrow][kq * 8]);
#pragma unroll
    for (int j = 0; j < 4; ++j)
      bfr[j] = *reinterpret_cast<const bf16x8*>(&lds_ab[1][wn + j * 16 + lrow][kq * 8]);
#pragma unroll
    for (int i = 0; i < 4; ++i)
#pragma unroll
      for (int j = 0; j < 4; ++j)
        acc[i][j] = __builtin_amdgcn_mfma_f32_16x16x32_bf16(af[i], bfr[j],
                                                            acc[i][j], 0, 0, 0);
    __syncthreads();
  }
#pragma unroll
  for (int i = 0; i < 4; ++i) {
    int mb = m0 + wm + i * 16 + kq * 4;
#pragma unroll
    for (int j = 0; j < 4; ++j) {
      int p = wn + j * 16 + lrow;
      if (p >= N) continue;
      float bv = bias[p];
#pragma unroll
      for (int reg = 0; reg < 4; ++reg) {
        int m = mb + reg;
        int b = m >> 11, c = m & 2047;
        float v = acc[i][j][reg] + bv;
        out[((ll)(b * Pn + p)) * Cn + c] = v * stdev[m] + mean[m];
      }
    }
  }
}

// =====================================================================
extern "C" void kernel_launch(void* const* d_in, const int* in_sizes, int n_in,
                              void* d_out, int out_size, void* d_ws, size_t ws_size,
                              hipStream_t stream) {
  (void)in_sizes; (void)n_in; (void)out_size; (void)ws_size;
  const float* x_enc = (const float*)d_in[0];
  const float* in_w = (const float*)d_in[4];
  const float* in_b = (const float*)d_in[5];
  const float* lq[3] = {(const float*)d_in[6], (const float*)d_in[7],
                        (const float*)d_in[8]};
  const float* down_w = (const float*)d_in[9];
  const float* down_b = (const float*)d_in[10];
  const float* down_ln = (const float*)d_in[11];
  const float* pred_w = (const float*)d_in[12];
  const float* pred_b = (const float*)d_in[13];
  const float* up_w = (const float*)d_in[14];
  const float* up_b = (const float*)d_in[15];
  const float* up_ln = (const float*)d_in[16];
  const float* out_w = (const float*)d_in[17];
  const float* out_b = (const float*)d_in[18];
  float* out = (float*)d_out;

  float* ws = (float*)d_ws;
  size_t off = 0;
  auto alloc = [&](size_t n) {
    n = (n + 3) & ~(size_t)3;  // 16B alignment
    float* p = ws + off;
    off += n;
    return p;
  };
  float* mean = alloc((size_t)Bn * Cn);
  float* stdevv = alloc((size_t)Bn * Cn);
  float* cmean = alloc(256);
  float* cistd = alloc(256);
  double* part = (double*)alloc(64 * 512 * 2);
  double* ld = (double*)alloc(16);
  double* covd = (double*)alloc(3 * 65536 * 2);
  float* s1 = alloc((size_t)Bn * 512 * Dn);
  float* s2 = alloc((size_t)Bn * 128 * Dn);
  float* s3 = alloc((size_t)Bn * 32 * Dn);
  float* attn = alloc((size_t)Bn * 512 * 2048);     // f32 scores; also xnT(bf16), xc
  float* sbuf = alloc((size_t)16777216);            // attn_bf / o2 f32 / covpart
  ushort_t* h_bf = (ushort_t*)alloc((size_t)Bn * Cn * Dn / 2);
  ushort_t* s1b = (ushort_t*)alloc((size_t)Bn * 512 * Dn / 2);
  ushort_t* s2b = (ushort_t*)alloc((size_t)Bn * 128 * Dn / 2);
  ushort_t* s3b = (ushort_t*)alloc((size_t)Bn * 32 * Dn / 2);
  ushort_t* xpb = (ushort_t*)alloc((size_t)Bn * 32 * Dn / 2);
  ushort_t* xu0b = (ushort_t*)alloc((size_t)Bn * 128 * Dn / 2);
  ushort_t* xu1b = (ushort_t*)alloc((size_t)Bn * 512 * Dn / 2);
  ushort_t* qd_b = (ushort_t*)alloc(512 * 256 / 2);
  ushort_t* lqb0 = (ushort_t*)alloc(512 * 256 / 2);
  ushort_t* lqb1 = (ushort_t*)alloc(128 * 256 / 2);
  ushort_t* lqb2 = (ushort_t*)alloc(32 * 256 / 2);
  ushort_t* in_wT = (ushort_t*)alloc(256 * SnP / 2);
  ushort_t* downT = (ushort_t*)alloc(12 * 65536 / 2);
  ushort_t* upT = (ushort_t*)alloc(12 * 65536 / 2);
  ushort_t* predT = (ushort_t*)alloc(65536 / 2);
  ushort_t* outT = (ushort_t*)alloc(96 * 256 / 2);
  ushort_t* q_bf = (ushort_t*)alloc((size_t)Bn * 2048 * Dn / 2);  // also o1, xph
  ushort_t* k_bf = (ushort_t*)alloc((size_t)Bn * 2048 * Dn / 2);
  ushort_t* vT = (ushort_t*)alloc((size_t)Bn * 2048 * Dn / 2);

  ushort_t* xnT = (ushort_t*)attn;
  ushort_t* attn_b = (ushort_t*)sbuf;
  float* o2 = sbuf;
  double* covpart = (double*)sbuf;
  const float scale = 0.0625f;
  const float* npf = nullptr;

  // ---- prep: stats, normalize+transpose input, weight converts ----
  instnorm_stats<<<dim3(Cn / 256, Bn), 256, 0, stream>>>(x_enc, mean, stdevv);
  normT_kernel<<<dim3(Cn / 32, SnP / 32, Bn), 256, 0, stream>>>(x_enc, xnT, mean,
                                                                stdevv);
  cvtT_kernel<<<dim3(8, 8, 12), 256, 0, stream>>>(down_w, downT, 256, 256, 256);
  cvtT_kernel<<<dim3(8, 8, 12), 256, 0, stream>>>(up_w, upT, 256, 256, 256);
  cvtT_kernel<<<dim3(8, 8, 1), 256, 0, stream>>>(pred_w, predT, 256, 256, 256);
  cvtT_kernel<<<dim3(8, SnP / 32, 1), 256, 0, stream>>>(in_w, in_wT, Sn, 256, SnP);
  cvtT_kernel<<<dim3(3, 8, 1), 256, 0, stream>>>(out_w, outT, 256, Pn, 256);
  cvt_bf<<<512, 256, 0, stream>>>(lq[0], lqb0, 512 * 256);
  cvt_bf<<<128, 256, 0, stream>>>(lq[1], lqb1, 128 * 256);
  cvt_bf<<<32, 256, 0, stream>>>(lq[2], lqb2, 32 * 256);

  // ---- h = xn^T @ in_w + b : bf16 out (K padded to 736) ----
  gemm_bf<2><<<dim3(2, 16, Bn), 256, 0, stream>>>(
      xnT, in_wT, Cn, Dn, SnP, SnP, SnP, (ll)Cn * SnP, 0, in_b, 1.f,
      nullptr, 0, 0, h_bf, Dn, (ll)Cn * Dn);

  ushort_t* lqb[3] = {lqb0, lqb1, lqb2};
  float* skf[3] = {s1, s2, s3};
  ushort_t* skb[3] = {s1b, s2b, s3b};
  int Ls[4] = {2048, 512, 128, 32};
  const ushort_t* xinb = h_bf;

  // ---------------- down layers ----------------
  for (int i = 0; i < 3; ++i) {
    int L = Ls[i], Lq = Ls[i + 1];
    const ushort_t* WqT = downT + (size_t)(i * 4 + 0) * 65536;
    const ushort_t* WkT = downT + (size_t)(i * 4 + 1) * 65536;
    const ushort_t* WvT = downT + (size_t)(i * 4 + 2) * 65536;
    const ushort_t* WoT = downT + (size_t)(i * 4 + 3) * 65536;
    const float* bq = down_b + (i * 4 + 0) * 256;
    const float* bk = down_b + (i * 4 + 1) * 256;
    const float* bv = down_b + (i * 4 + 2) * 256;
    const float* bo = down_b + (i * 4 + 3) * 256;

    gemm_bf<2><<<dim3(2, CDIV(Lq, 128), 1), 256, 0, stream>>>(
        lqb[i], WqT, Lq, Dn, Dn, Dn, Dn, 0, 0, bq, 1.f, nullptr, 0, 0, qd_b, Dn, 0);
    gemm_bf<2><<<dim3(2, (Bn * L) / 128, 1), 256, 0, stream>>>(
        xinb, WkT, Bn * L, Dn, Dn, Dn, Dn, 0, 0, bk, 1.f, nullptr, 0, 0, k_bf, Dn, 0);
    gemm_bf<4><<<dim3(2, L / 128, Bn), 256, 0, stream>>>(
        xinb, WvT, L, Dn, Dn, Dn, Dn, (ll)L * Dn, 0, bv, 1.f, nullptr, 0, 0,
        vT, L, (ll)Dn * L);
    gemm_bf<1><<<dim3(L / 128, CDIV(Lq, 128), Bn), 256, 0, stream>>>(
        qd_b, k_bf, Lq, L, Dn, Dn, Dn, 0, (ll)L * Dn, npf, scale,
        attn, L, (ll)Lq * L, nullptr, 0, 0);
    if (L == 2048) softmax_bf<2048><<<Bn * Lq, 256, 0, stream>>>(attn, attn_b);
    else if (L == 512) softmax_bf<512><<<Bn * Lq, 256, 0, stream>>>(attn, attn_b);
    else softmax_bf<128><<<Bn * Lq, 256, 0, stream>>>(attn, attn_b);
    gemm_bf<2><<<dim3(2, CDIV(Lq, 128), Bn), 256, 0, stream>>>(
        attn_b, vT, Lq, Dn, L, L, L, (ll)Lq * L, (ll)Dn * L, npf, 1.f,
        nullptr, 0, 0, q_bf, Dn, (ll)Lq * Dn);
    gemm_bf<1><<<dim3(2, CDIV(Bn * Lq, 128), 1), 256, 0, stream>>>(
        q_bf, WoT, Bn * Lq, Dn, Dn, Dn, Dn, 0, 0, bo, 1.f, o2, Dn, 0, nullptr, 0, 0);
    ln_kernel<<<Bn * Lq, 256, 0, stream>>>(o2, nullptr, skf[i], skb[i], 0,
                                           down_ln + (i * 2 + 0) * 256,
                                           down_ln + (i * 2 + 1) * 256);
    xinb = skb[i];
  }

  // ---------------- covariance loss (split-K f64 Gram + reg-panel Cholesky) ---
  int nrs[3] = {Bn * 512, Bn * 128, Bn * 32};
  float* xc = attn;
  for (int j = 0; j < 3; ++j) {
    int nr = nrs[j];
    colstat_partial<<<64, 256, 0, stream>>>(skf[j], part, nr);
    colstat_final<<<1, 256, 0, stream>>>(part, cmean, cistd, nr);
    xcnorm_kernel<<<1024, 256, 0, stream>>>(skf[j], xc, cmean, cistd, (ll)nr * Dn);
    cov_gemm_f64_split<<<dim3(8, 8, 16), 256, 0, stream>>>(xc, covpart, nr);
    cov_reduce<<<256, 256, 0, stream>>>(covpart, covd + (size_t)j * 65536,
                                        1.0 / (double)(nr - 1));
  }
  cholesky_logdet_f64<<<3, 1024, 0, stream>>>(covd, ld);
  cov_final<<<1, 1, 0, stream>>>(ld, out + 6291456);

  // ---------------- pred head ----------------
  gemm_bf<2><<<dim3(2, 8, 1), 256, 0, stream>>>(
      s3b, predT, Bn * 32, Dn, Dn, Dn, Dn, 0, 0, pred_b, 1.f,
      nullptr, 0, 0, xpb, Dn, 0);

  // ---------------- up layers ----------------
  int Lks[3] = {32, 128, 512}, Lqs[3] = {128, 512, 2048};
  const ushort_t* qinb[3] = {s2b, s1b, h_bf};
  const ushort_t* xinbs[3] = {xpb, xu0b, xu1b};
  ushort_t* xoutb[3] = {xu0b, xu1b, q_bf};  // final writes xph into q_bf
  for (int i = 0; i < 3; ++i) {
    int Lk = Lks[i], Lq = Lqs[i];
    const ushort_t* WqT = upT + (size_t)(i * 4 + 0) * 65536;
    const ushort_t* WkT = upT + (size_t)(i * 4 + 1) * 65536;
    const ushort_t* WvT = upT + (size_t)(i * 4 + 2) * 65536;
    const ushort_t* WoT = upT + (size_t)(i * 4 + 3) * 65536;
    const float* bq = up_b + (i * 4 + 0) * 256;
    const float* bk = up_b + (i * 4 + 1) * 256;
    const float* bv = up_b + (i * 4 + 2) * 256;
    const float* bo = up_b + (i * 4 + 3) * 256;

    gemm_bf<2><<<dim3(2, (Bn * Lq) / 128, 1), 256, 0, stream>>>(
        qinb[i], WqT, Bn * Lq, Dn, Dn, Dn, Dn, 0, 0, bq, 1.f,
        nullptr, 0, 0, q_bf, Dn, 0);
    gemm_bf<2><<<dim3(2, CDIV(Bn * Lk, 128), 1), 256, 0, stream>>>(
        xinbs[i], WkT, Bn * Lk, Dn, Dn, Dn, Dn, 0, 0, bk, 1.f,
        nullptr, 0, 0, k_bf, Dn, 0);
    gemm_bf<4><<<dim3(2, CDIV(Lk, 128), Bn), 256, 0, stream>>>(
        xinbs[i], WvT, Lk, Dn, Dn, Dn, Dn, (ll)Lk * Dn, 0, bv, 1.f,
        nullptr, 0, 0, vT, Lk, (ll)Dn * Lk);
    gemm_bf<1><<<dim3(CDIV(Lk, 128), CDIV(Lq, 128), Bn), 256, 0, stream>>>(
        q_bf, k_bf, Lq, Lk, Dn, Dn, Dn, (ll)Lq * Dn, (ll)Lk * Dn, npf, scale,
        attn, Lk, (ll)Lq * Lk, nullptr, 0, 0);
    if (Lk == 32) softmax_bf<32><<<Bn * Lq, 256, 0, stream>>>(attn, attn_b);
    else if (Lk == 128) softmax_bf<128><<<Bn * Lq, 256, 0, stream>>>(attn, attn_b);
    else softmax_bf<512><<<Bn * Lq, 256, 0, stream>>>(attn, attn_b);
    gemm_bf<2><<<dim3(2, CDIV(Lq, 128), Bn), 256, 0, stream>>>(
        attn_b, vT, Lq, Dn, Lk, Lk, Lk, (ll)Lq * Lk, (ll)Dn * Lk, npf, 1.f,
        nullptr, 0, 0, q_bf, Dn, (ll)Lq * Dn);
    gemm_bf<1><<<dim3(2, (Bn * Lq) / 128, 1), 256, 0, stream>>>(
        q_bf, WoT, Bn * Lq, Dn, Dn, Dn, Dn, 0, 0, bo, 1.f, o2, Dn, 0, nullptr, 0, 0);
    ln_kernel<<<Bn * Lq, 256, 0, stream>>>(o2, qinb[i], nullptr, xoutb[i],
                                           (i == 2) ? 1 : 0,
                                           up_ln + (i * 2 + 0) * 256,
                                           up_ln + (i * 2 + 1) * 256);
  }

  // ---------------- output head: MFMA + transpose + de-norm ----------------
  out_mfma<<<dim3(1, (Bn * Cn) / 128, 1), 256, 0, stream>>>(q_bf, outT, out_b,
                                                            stdevv, mean, out);
}